// Round 1
// baseline (20661.168 us; speedup 1.0000x reference)
//
#include <hip/hip_runtime.h>
#include <math.h>

#define T_TOK 2056
#define HIDDEN 512
#define NHEAD 8
#define ADIM 64
#define FFDIM 2048
#define NLAYER 6
#define NORIG 520
#define NOBJ 8

// ---------------- block reduction helpers (256 threads = 4 waves) ----------------

__device__ inline float blockReduceSum(float v, float* sb) {
#pragma unroll
  for (int off = 32; off > 0; off >>= 1) v += __shfl_down(v, off, 64);
  int wid = threadIdx.x >> 6;
  __syncthreads();  // protect sb from previous use
  if ((threadIdx.x & 63) == 0) sb[wid] = v;
  __syncthreads();
  return sb[0] + sb[1] + sb[2] + sb[3];
}

__device__ inline float blockReduceMax(float v, float* sb) {
#pragma unroll
  for (int off = 32; off > 0; off >>= 1) v = fmaxf(v, __shfl_down(v, off, 64));
  int wid = threadIdx.x >> 6;
  __syncthreads();
  if ((threadIdx.x & 63) == 0) sb[wid] = v;
  __syncthreads();
  return fmaxf(fmaxf(sb[0], sb[1]), fmaxf(sb[2], sb[3]));
}

// ---------------- token embedding: project + LN + leaky_relu ----------------
// one block per token, 256 threads, each thread owns dims (tid, tid+256)

__global__ __launch_bounds__(256) void embed_kernel(
    const float* __restrict__ obj, const float* __restrict__ st0,
    const float* __restrict__ Wpg, const float* __restrict__ bpg,
    const float* __restrict__ pg_g, const float* __restrict__ pg_b,
    const float* __restrict__ Wps, const float* __restrict__ bps,
    const float* __restrict__ ps_g, const float* __restrict__ ps_b,
    float* __restrict__ x)
{
  __shared__ float sb[4];
  int t = blockIdx.x;
  int j0 = threadIdx.x, j1 = threadIdx.x + 256;
  float a0, a1;
  const float *g, *b;
  if (t < NOBJ) {
    a0 = bpg[j0]; a1 = bpg[j1];
    const float* in = obj + t * 100;  // (8, 25, 4) -> (8, 100)
    for (int i = 0; i < 100; i++) {
      float w = in[i];
      a0 += w * Wpg[i * HIDDEN + j0];
      a1 += w * Wpg[i * HIDDEN + j1];
    }
    g = pg_g; b = pg_b;
  } else {
    int tt = t - NOBJ, s = tt >> 2, p = tt & 3;
    float c0 = st0[s * 10 + p * 2], c1 = st0[s * 10 + p * 2 + 1];
    a0 = bps[j0] + c0 * Wps[j0] + c1 * Wps[HIDDEN + j0];
    a1 = bps[j1] + c0 * Wps[j1] + c1 * Wps[HIDDEN + j1];
    g = ps_g; b = ps_b;
  }
  float s1 = blockReduceSum(a0 + a1, sb);
  float s2 = blockReduceSum(a0 * a0 + a1 * a1, sb);
  float m = s1 * (1.0f / HIDDEN);
  float var = s2 * (1.0f / HIDDEN) - m * m;
  float inv = rsqrtf(var + 1e-5f);
  float y0 = (a0 - m) * inv * g[j0] + b[j0];
  float y1 = (a1 - m) * inv * g[j1] + b[j1];
  y0 = y0 >= 0.f ? y0 : 0.01f * y0;
  y1 = y1 >= 0.f ? y1 : 0.01f * y1;
  x[(long long)t * HIDDEN + j0] = y0;
  x[(long long)t * HIDDEN + j1] = y1;
}

// ---------------- generic fp32 tiled GEMM: C = A @ B (+bias)(+leaky) ----------------
// BM=BN=64, BK=16; 256 threads, 4x4 per thread; split-K via blockIdx.z

__global__ __launch_bounds__(256) void gemm_nn(
    const float* __restrict__ A, int lda,
    const float* __restrict__ B, int ldb,
    const float* __restrict__ bias,
    float* __restrict__ C, int ldc,
    int M, int N, int K0, int K1, int act,
    int splitLen, long long splitStride)
{
  __shared__ __align__(16) float As[16][68];  // As[k][m], padded stride
  __shared__ __align__(16) float Bs[16][64];  // Bs[k][n]
  int tid = threadIdx.x;
  int tx = tid & 15, ty = tid >> 4;
  int rowBase = blockIdx.y * 64, colBase = blockIdx.x * 64;
  int z = blockIdx.z;
  int k0 = K0 + z * splitLen;
  int k1 = min(K1, k0 + splitLen);
  C += (long long)z * splitStride;
  float acc[4][4] = {};
  for (int kb = k0; kb < k1; kb += 16) {
#pragma unroll
    for (int i = 0; i < 4; i++) {
      int e = tid + 256 * i; int r = e >> 4, c = e & 15;
      int row = rowBase + r, kk = kb + c;
      As[c][r] = (row < M && kk < k1) ? A[(long long)row * lda + kk] : 0.f;
    }
#pragma unroll
    for (int i = 0; i < 4; i++) {
      int e = tid + 256 * i; int r = e >> 6, c = e & 63;
      int kk = kb + r, col = colBase + c;
      Bs[r][c] = (kk < k1 && col < N) ? B[(long long)kk * ldb + col] : 0.f;
    }
    __syncthreads();
#pragma unroll
    for (int kk = 0; kk < 16; kk++) {
      float4 av = *(const float4*)&As[kk][ty * 4];
      float4 bv = *(const float4*)&Bs[kk][tx * 4];
      float ar[4] = {av.x, av.y, av.z, av.w};
      float br[4] = {bv.x, bv.y, bv.z, bv.w};
#pragma unroll
      for (int i = 0; i < 4; i++)
#pragma unroll
        for (int j = 0; j < 4; j++)
          acc[i][j] += ar[i] * br[j];
    }
    __syncthreads();
  }
#pragma unroll
  for (int i = 0; i < 4; i++) {
    int row = rowBase + ty * 4 + i;
    if (row >= M) continue;
#pragma unroll
    for (int j = 0; j < 4; j++) {
      int col = colBase + tx * 4 + j;
      if (col >= N) continue;
      float v = acc[i][j];
      if (bias) v += bias[col];
      if (act) v = v >= 0.f ? v : 0.01f * v;
      C[(long long)row * ldc + col] = v;
    }
  }
}

// ---------------- scores: S = (Q Kh^T + pos) * 1/8 + mask, per head ----------------

__global__ __launch_bounds__(256) void scores_nt(
    const float* __restrict__ q, const float* __restrict__ kmat,
    float* __restrict__ S,
    const int* __restrict__ rpe_a, const int* __restrict__ rpe_d,
    const float* __restrict__ emb_a, const float* __restrict__ emb_d,
    const float* __restrict__ mask, int h)
{
  __shared__ __align__(16) float As[16][68];  // As[k][m]
  __shared__ __align__(16) float Bs[16][68];  // Bs[k][n] = K[n][k]
  int tid = threadIdx.x;
  int tx = tid & 15, ty = tid >> 4;
  int rowBase = blockIdx.y * 64, colBase = blockIdx.x * 64;
  const float* qh = q + h * ADIM;
  const float* kh = kmat + h * ADIM;
  float acc[4][4] = {};
#pragma unroll
  for (int kb = 0; kb < ADIM; kb += 16) {
#pragma unroll
    for (int i = 0; i < 4; i++) {
      int e = tid + 256 * i; int r = e >> 4, c = e & 15;
      int row = rowBase + r;
      As[c][r] = (row < T_TOK) ? qh[(long long)row * HIDDEN + kb + c] : 0.f;
    }
#pragma unroll
    for (int i = 0; i < 4; i++) {
      int e = tid + 256 * i; int r = e >> 4, c = e & 15;
      int col = colBase + r;
      Bs[c][r] = (col < T_TOK) ? kh[(long long)col * HIDDEN + kb + c] : 0.f;
    }
    __syncthreads();
#pragma unroll
    for (int kk = 0; kk < 16; kk++) {
      float4 av = *(const float4*)&As[kk][ty * 4];
      float4 bv = *(const float4*)&Bs[kk][tx * 4];
      float ar[4] = {av.x, av.y, av.z, av.w};
      float br[4] = {bv.x, bv.y, bv.z, bv.w};
#pragma unroll
      for (int i = 0; i < 4; i++)
#pragma unroll
        for (int j = 0; j < 4; j++)
          acc[i][j] += ar[i] * br[j];
    }
    __syncthreads();
  }
#pragma unroll
  for (int i = 0; i < 4; i++) {
    int row = rowBase + ty * 4 + i;
    if (row >= T_TOK) continue;
    int oq = row < NOBJ ? row : NOBJ + ((row - NOBJ) >> 2);
#pragma unroll
    for (int j = 0; j < 4; j++) {
      int col = colBase + tx * 4 + j;
      if (col >= T_TOK) continue;
      int ok = col < NOBJ ? col : NOBJ + ((col - NOBJ) >> 2);
      int idx = oq * NORIG + ok;
      float pos = emb_a[rpe_a[idx] * NHEAD + h] + emb_d[rpe_d[idx] * NHEAD + h];
      float v = (acc[i][j] + pos) * 0.125f + mask[idx];
      S[(long long)row * T_TOK + col] = v;
    }
  }
}

// ---------------- row softmax over 2056 columns, in place ----------------

__global__ __launch_bounds__(256) void softmax_rows(float* __restrict__ S)
{
  __shared__ float sb[4];
  int row = blockIdx.x;
  float* p = S + (long long)row * T_TOK;
  int tid = threadIdx.x;
  float r[9];
  float mx = -3.4e38f;
#pragma unroll
  for (int i = 0; i < 9; i++) {
    int c = tid + 256 * i;
    r[i] = (c < T_TOK) ? p[c] : -3.4e38f;
    mx = fmaxf(mx, r[i]);
  }
  mx = blockReduceMax(mx, sb);
  float s = 0.f;
#pragma unroll
  for (int i = 0; i < 9; i++) {
    int c = tid + 256 * i;
    if (c < T_TOK) { r[i] = __expf(r[i] - mx); s += r[i]; }
  }
  s = blockReduceSum(s, sb);
  float inv = 1.0f / s;
#pragma unroll
  for (int i = 0; i < 9; i++) {
    int c = tid + 256 * i;
    if (c < T_TOK) p[c] = r[i] * inv;
  }
}

// ---------------- reduce split-K PV partials into o[:, h*64:(h+1)*64] ----------------

__global__ __launch_bounds__(256) void reduce_pv(
    const float* __restrict__ parts, float* __restrict__ o, int h)
{
  int idx = blockIdx.x * 256 + threadIdx.x;
  if (idx >= T_TOK * ADIM) return;
  float s = 0.f;
#pragma unroll
  for (int z = 0; z < 16; z++) s += parts[(long long)z * (T_TOK * ADIM) + idx];
  int qrow = idx >> 6, d = idx & 63;
  o[(long long)qrow * HIDDEN + h * ADIM + d] = s;
}

// ---------------- residual + LN, in place on x ----------------

__global__ __launch_bounds__(256) void ln_residual(
    float* __restrict__ x, const float* __restrict__ delta,
    const float* __restrict__ g, const float* __restrict__ b)
{
  __shared__ float sb[4];
  int row = blockIdx.x;
  int j0 = threadIdx.x, j1 = threadIdx.x + 256;
  long long base = (long long)row * HIDDEN;
  float v0 = x[base + j0] + delta[base + j0];
  float v1 = x[base + j1] + delta[base + j1];
  float s1 = blockReduceSum(v0 + v1, sb);
  float s2 = blockReduceSum(v0 * v0 + v1 * v1, sb);
  float m = s1 * (1.0f / HIDDEN);
  float var = s2 * (1.0f / HIDDEN) - m * m;
  float inv = rsqrtf(var + 1e-5f);
  x[base + j0] = (v0 - m) * inv * g[j0] + b[j0];
  x[base + j1] = (v1 - m) * inv * g[j1] + b[j1];
}

__global__ __launch_bounds__(256) void copy_out(
    const float4* __restrict__ src, float4* __restrict__ dst, int n4)
{
  int i = blockIdx.x * 256 + threadIdx.x;
  if (i < n4) dst[i] = src[i];
}

// ---------------- driver ----------------

extern "C" void kernel_launch(void* const* d_in, const int* in_sizes, int n_in,
                              void* d_out, int out_size, void* d_ws, size_t ws_size,
                              hipStream_t stream) {
  const float* obj   = (const float*)d_in[0];
  // d_in[1] obj_scale: unused by reference
  const float* st0   = (const float*)d_in[2];
  const int*   rpe_a = (const int*)d_in[3];
  const int*   rpe_d = (const int*)d_in[4];
  const float* mask  = (const float*)d_in[5];
  const float* Wpg = (const float*)d_in[6];  const float* bpg = (const float*)d_in[7];
  const float* pg_g = (const float*)d_in[8]; const float* pg_b = (const float*)d_in[9];
  const float* Wps = (const float*)d_in[10]; const float* bps = (const float*)d_in[11];
  const float* ps_g = (const float*)d_in[12];const float* ps_b = (const float*)d_in[13];
  const float* emb_a = (const float*)d_in[14];
  const float* emb_d = (const float*)d_in[15];
  const float* Wq = (const float*)d_in[16]; const float* bq = (const float*)d_in[17];
  const float* Wk = (const float*)d_in[18]; const float* bk = (const float*)d_in[19];
  const float* Wv = (const float*)d_in[20]; const float* bv = (const float*)d_in[21];
  const float* Wo = (const float*)d_in[22]; const float* bo = (const float*)d_in[23];
  const float* W1 = (const float*)d_in[24]; const float* b1 = (const float*)d_in[25];
  const float* W2 = (const float*)d_in[26]; const float* b2 = (const float*)d_in[27];
  const float* ln1_g = (const float*)d_in[28]; const float* ln1_b = (const float*)d_in[29];
  const float* ln2_g = (const float*)d_in[30]; const float* ln2_b = (const float*)d_in[31];

  const long long TH = (long long)T_TOK * HIDDEN;          // 1,052,672
  float* ws = (float*)d_ws;
  float* x    = ws;
  float* qb   = x + TH;
  float* kb   = qb + TH;
  float* vb   = kb + TH;
  float* ob   = vb + TH;
  float* big  = ob + TH;                 // max(T*T, T*FF) = 4,227,136 floats
  float* paux = big + 4227136;           // 16 * T * 64 = 2,105,344 floats
  size_t needed = (size_t)(5 * TH + 4227136 + 2105344) * sizeof(float);
  if (ws_size < needed) return;  // workspace too small; fail loudly rather than corrupt

  float* out = (float*)d_out;

  embed_kernel<<<T_TOK, 256, 0, stream>>>(obj, st0, Wpg, bpg, pg_g, pg_b,
                                          Wps, bps, ps_g, ps_b, x);

  const int MB = (T_TOK + 63) / 64;  // 33
  for (int l = 0; l < NLAYER; l++) {
    const float* Wql = Wq + (long long)l * HIDDEN * HIDDEN;
    const float* Wkl = Wk + (long long)l * HIDDEN * HIDDEN;
    const float* Wvl = Wv + (long long)l * HIDDEN * HIDDEN;
    const float* Wol = Wo + (long long)l * HIDDEN * HIDDEN;
    const float* W1l = W1 + (long long)l * HIDDEN * FFDIM;
    const float* W2l = W2 + (long long)l * FFDIM * HIDDEN;

    // QKV projections
    gemm_nn<<<dim3(HIDDEN / 64, MB, 1), 256, 0, stream>>>(
        x, HIDDEN, Wql, HIDDEN, bq + l * HIDDEN, qb, HIDDEN,
        T_TOK, HIDDEN, 0, HIDDEN, 0, HIDDEN, 0);
    gemm_nn<<<dim3(HIDDEN / 64, MB, 1), 256, 0, stream>>>(
        x, HIDDEN, Wkl, HIDDEN, bk + l * HIDDEN, kb, HIDDEN,
        T_TOK, HIDDEN, 0, HIDDEN, 0, HIDDEN, 0);
    gemm_nn<<<dim3(HIDDEN / 64, MB, 1), 256, 0, stream>>>(
        x, HIDDEN, Wvl, HIDDEN, bv + l * HIDDEN, vb, HIDDEN,
        T_TOK, HIDDEN, 0, HIDDEN, 0, HIDDEN, 0);

    // attention, head by head (scores buffer reused)
    for (int h = 0; h < NHEAD; h++) {
      scores_nt<<<dim3(MB, MB, 1), 256, 0, stream>>>(
          qb, kb, big, rpe_a, rpe_d, emb_a, emb_d, mask, h);
      softmax_rows<<<T_TOK, 256, 0, stream>>>(big);
      // PV: [T,T] @ [T,64], 16-way split-K into paux
      gemm_nn<<<dim3(1, MB, 16), 256, 0, stream>>>(
          big, T_TOK, vb + h * ADIM, HIDDEN, nullptr, paux, ADIM,
          T_TOK, ADIM, 0, T_TOK, 0, 129, (long long)T_TOK * ADIM);
      reduce_pv<<<(T_TOK * ADIM + 255) / 256, 256, 0, stream>>>(paux, ob, h);
    }

    // output projection -> paux (reused as tmp), then x = LN(x + tmp)
    gemm_nn<<<dim3(HIDDEN / 64, MB, 1), 256, 0, stream>>>(
        ob, HIDDEN, Wol, HIDDEN, bo + l * HIDDEN, paux, HIDDEN,
        T_TOK, HIDDEN, 0, HIDDEN, 0, HIDDEN, 0);
    ln_residual<<<T_TOK, 256, 0, stream>>>(x, paux, ln1_g + l * HIDDEN, ln1_b + l * HIDDEN);

    // FFN
    gemm_nn<<<dim3(FFDIM / 64, MB, 1), 256, 0, stream>>>(
        x, HIDDEN, W1l, FFDIM, b1 + l * FFDIM, big, FFDIM,
        T_TOK, FFDIM, 0, HIDDEN, 1, HIDDEN, 0);
    gemm_nn<<<dim3(HIDDEN / 64, MB, 1), 256, 0, stream>>>(
        big, FFDIM, W2l, HIDDEN, b2 + l * HIDDEN, paux, HIDDEN,
        T_TOK, HIDDEN, 0, FFDIM, 0, FFDIM, 0);
    ln_residual<<<T_TOK, 256, 0, stream>>>(x, paux, ln2_g + l * HIDDEN, ln2_b + l * HIDDEN);
  }

  int n4 = (int)(TH / 4);
  copy_out<<<(n4 + 255) / 256, 256, 0, stream>>>((const float4*)x, (float4*)out, n4);
}

// Round 2
// 1851.531 us; speedup vs baseline: 11.1590x; 11.1590x over previous
//
#include <hip/hip_runtime.h>
#include <math.h>

#define T_TOK 2056
#define TP 2176      // 17*128  M-padded rows
#define TK 2112      // 33*64   KV-padded rows
#define HIDDEN 512
#define NHEAD 8
#define ADIM 64
#define FFDIM 2048
#define NLAYER 6
#define NORIG 520
#define NOBJ 8

typedef float f32x4 __attribute__((ext_vector_type(4)));
typedef __attribute__((__ext_vector_type__(8))) __bf16 bf16x8;

__device__ __forceinline__ unsigned short f2bf(float f) {
  unsigned int u = __float_as_uint(f);
  u += 0x7FFFu + ((u >> 16) & 1u);
  return (unsigned short)(u >> 16);
}

// ---------------- block reduction helpers (256 threads = 4 waves) ----------------

__device__ inline float blockReduceSum(float v, float* sb) {
#pragma unroll
  for (int off = 32; off > 0; off >>= 1) v += __shfl_down(v, off, 64);
  int wid = threadIdx.x >> 6;
  __syncthreads();
  if ((threadIdx.x & 63) == 0) sb[wid] = v;
  __syncthreads();
  return sb[0] + sb[1] + sb[2] + sb[3];
}

// ---------------- token embedding: project + LN + leaky_relu (fp32 + bf16 mirror) ----

__global__ __launch_bounds__(256) void embed_kernel(
    const float* __restrict__ obj, const float* __restrict__ st0,
    const float* __restrict__ Wpg, const float* __restrict__ bpg,
    const float* __restrict__ pg_g, const float* __restrict__ pg_b,
    const float* __restrict__ Wps, const float* __restrict__ bps,
    const float* __restrict__ ps_g, const float* __restrict__ ps_b,
    float* __restrict__ x, unsigned short* __restrict__ xb)
{
  __shared__ float sb[4];
  int t = blockIdx.x;
  int j0 = threadIdx.x, j1 = threadIdx.x + 256;
  float a0, a1;
  const float *g, *b;
  if (t < NOBJ) {
    a0 = bpg[j0]; a1 = bpg[j1];
    const float* in = obj + t * 100;
    for (int i = 0; i < 100; i++) {
      float w = in[i];
      a0 += w * Wpg[i * HIDDEN + j0];
      a1 += w * Wpg[i * HIDDEN + j1];
    }
    g = pg_g; b = pg_b;
  } else {
    int tt = t - NOBJ, s = tt >> 2, p = tt & 3;
    float c0 = st0[s * 10 + p * 2], c1 = st0[s * 10 + p * 2 + 1];
    a0 = bps[j0] + c0 * Wps[j0] + c1 * Wps[HIDDEN + j0];
    a1 = bps[j1] + c0 * Wps[j1] + c1 * Wps[HIDDEN + j1];
    g = ps_g; b = ps_b;
  }
  float s1 = blockReduceSum(a0 + a1, sb);
  float s2 = blockReduceSum(a0 * a0 + a1 * a1, sb);
  float m = s1 * (1.0f / HIDDEN);
  float var = s2 * (1.0f / HIDDEN) - m * m;
  float inv = rsqrtf(var + 1e-5f);
  float y0 = (a0 - m) * inv * g[j0] + b[j0];
  float y1 = (a1 - m) * inv * g[j1] + b[j1];
  y0 = y0 >= 0.f ? y0 : 0.01f * y0;
  y1 = y1 >= 0.f ? y1 : 0.01f * y1;
  x[t * HIDDEN + j0] = y0;
  x[t * HIDDEN + j1] = y1;
  xb[t * HIDDEN + j0] = f2bf(y0);
  xb[t * HIDDEN + j1] = f2bf(y1);
}

// zero xb pad rows (re-run every launch; ws is re-poisoned)
__global__ __launch_bounds__(256) void padzero(unsigned short* __restrict__ xb) {
  int i = blockIdx.x * 256 + threadIdx.x;
  if (i < (TP - T_TOK) * HIDDEN) xb[T_TOK * HIDDEN + i] = 0;
}

// ---------------- weight transpose+convert: fp32 [K][N] -> bf16 [N][K], all mats of a layer

__global__ __launch_bounds__(256) void wtrans(
    const float* __restrict__ Wq, const float* __restrict__ Wk, const float* __restrict__ Wv,
    const float* __restrict__ Wo, const float* __restrict__ W1, const float* __restrict__ W2,
    unsigned short* __restrict__ Wqkvt, unsigned short* __restrict__ Wot,
    unsigned short* __restrict__ W1t, unsigned short* __restrict__ W2t)
{
  __shared__ float t[64 * 65];
  int b = blockIdx.x;
  const float* src; unsigned short* dst; int N, K, tk, tn;
  if (b < 192) {
    int m = b >> 6, bb = b & 63;
    src = m == 0 ? Wq : m == 1 ? Wk : Wv;
    dst = Wqkvt + m * 512 * 512;
    K = 512; N = 512; tk = bb & 7; tn = bb >> 3;
  } else if (b < 256) {
    int bb = b - 192; src = Wo; dst = Wot; K = 512; N = 512; tk = bb & 7; tn = bb >> 3;
  } else if (b < 512) {
    int bb = b - 256; src = W1; dst = W1t; K = 512; N = 2048; tk = bb & 7; tn = bb >> 3;
  } else {
    int bb = b - 512; src = W2; dst = W2t; K = 2048; N = 512; tk = bb & 31; tn = bb >> 5;
  }
  int k0 = tk * 64, n0 = tn * 64;
  int tid = threadIdx.x;
  int r = tid >> 2, c0 = (tid & 3) * 16;
  const float* sp = src + (k0 + r) * N + n0 + c0;
#pragma unroll
  for (int q = 0; q < 4; q++) {
    float4 f = *(const float4*)(sp + q * 4);
    t[r * 65 + c0 + q * 4 + 0] = f.x;
    t[r * 65 + c0 + q * 4 + 1] = f.y;
    t[r * 65 + c0 + q * 4 + 2] = f.z;
    t[r * 65 + c0 + q * 4 + 3] = f.w;
  }
  __syncthreads();
  unsigned short vals[16];
#pragma unroll
  for (int j = 0; j < 16; j++) vals[j] = f2bf(t[(c0 + j) * 65 + r]);
  unsigned short* dp = dst + (n0 + r) * K + k0 + c0;
  *(int4*)dp = *(int4*)&vals[0];
  *(int4*)(dp + 8) = *(int4*)&vals[8];
}

// ---------------- MFMA GEMM: C[M=2176][N] = A[.][K] * Bt[N][K]^T, bf16 in / fp32 acc ----
// 128x128 tile, 4 waves each 64x64 (4x4 of 16x16x32). LDS stride 56 (112B: 16B-aligned,
// 2-way bank aliasing only = free).
// mode 0: +bias(seg) -> scatter bf16 to qh/kh/vh [head][TP][64]
// mode 1: +bias -> fp32 df
// mode 2: +bias, leaky -> bf16 d0

__global__ __launch_bounds__(256) void gemm_bt(
    const unsigned short* __restrict__ A, int lda,
    const unsigned short* __restrict__ Bt, int ldb, int K, int mode,
    const float* __restrict__ b0, const float* __restrict__ b1, const float* __restrict__ b2,
    unsigned short* __restrict__ d0, unsigned short* __restrict__ d1, unsigned short* __restrict__ d2,
    float* __restrict__ df, int ldc)
{
  __shared__ unsigned short As[128 * 56];
  __shared__ unsigned short Bs[128 * 56];
  const int tid = threadIdx.x;
  const int lane = tid & 63, wave = tid >> 6;
  const int l15 = lane & 15, quad = lane >> 4;
  const int rowBase = blockIdx.y * 128, colBase = blockIdx.x * 128;
  const int mw = (wave >> 1) * 64, nw = (wave & 1) * 64;
  const int sr = tid >> 2, sc = (tid & 3) * 8;
  const unsigned short* Ag0 = A + (rowBase + sr) * lda + sc;
  const unsigned short* Ag1 = Ag0 + 64 * lda;
  const unsigned short* Bg0 = Bt + (colBase + sr) * ldb + sc;
  const unsigned short* Bg1 = Bg0 + 64 * ldb;
  f32x4 acc[4][4];
#pragma unroll
  for (int i = 0; i < 4; i++)
#pragma unroll
    for (int j = 0; j < 4; j++) acc[i][j] = (f32x4){0.f, 0.f, 0.f, 0.f};

  for (int kb = 0; kb < K; kb += 32) {
    int4 a0 = *(const int4*)(Ag0 + kb);
    int4 a1 = *(const int4*)(Ag1 + kb);
    int4 g0 = *(const int4*)(Bg0 + kb);
    int4 g1 = *(const int4*)(Bg1 + kb);
    __syncthreads();
    *(int4*)&As[sr * 56 + sc] = a0;
    *(int4*)&As[(sr + 64) * 56 + sc] = a1;
    *(int4*)&Bs[sr * 56 + sc] = g0;
    *(int4*)&Bs[(sr + 64) * 56 + sc] = g1;
    __syncthreads();
    bf16x8 af[4], bfr[4];
#pragma unroll
    for (int mt = 0; mt < 4; mt++)
      af[mt] = *(const bf16x8*)&As[(mw + mt * 16 + l15) * 56 + quad * 8];
#pragma unroll
    for (int nt = 0; nt < 4; nt++)
      bfr[nt] = *(const bf16x8*)&Bs[(nw + nt * 16 + l15) * 56 + quad * 8];
#pragma unroll
    for (int mt = 0; mt < 4; mt++)
#pragma unroll
      for (int nt = 0; nt < 4; nt++)
        acc[mt][nt] = __builtin_amdgcn_mfma_f32_16x16x32_bf16(af[mt], bfr[nt], acc[mt][nt], 0, 0, 0);
  }

#pragma unroll
  for (int mt = 0; mt < 4; mt++) {
#pragma unroll
    for (int nt = 0; nt < 4; nt++) {
#pragma unroll
      for (int r = 0; r < 4; r++) {
        int row = rowBase + mw + mt * 16 + quad * 4 + r;
        int col = colBase + nw + nt * 16 + l15;
        float v = acc[mt][nt][r];
        if (mode == 0) {
          int seg = col >> 9, cc = col & 511;
          const float* bs = seg == 0 ? b0 : seg == 1 ? b1 : b2;
          unsigned short* dst = seg == 0 ? d0 : seg == 1 ? d1 : d2;
          int hd = cc >> 6, d = cc & 63;
          dst[(hd * TP + row) * 64 + d] = f2bf(v + bs[cc]);
        } else if (mode == 1) {
          df[row * ldc + col] = v + b0[col];
        } else {
          float t = v + b0[col];
          t = t >= 0.f ? t : 0.01f * t;
          d0[row * ldc + col] = f2bf(t);
        }
      }
    }
  }
}

// ---------------- V transpose: vh [h][TP][64] -> vt [h][64][TK] ----------------

__global__ __launch_bounds__(256) void vt_trans(
    const unsigned short* __restrict__ vh, unsigned short* __restrict__ vt)
{
  __shared__ unsigned short t[64 * 72];
  int kt = blockIdx.x, h = blockIdx.y;
  int tid = threadIdx.x;
  int r0 = tid >> 3, cs = (tid & 7) * 8;
  const unsigned short* src = vh + (h * TP + kt * 64 + r0) * 64 + cs;
  *(int4*)&t[r0 * 72 + cs] = *(const int4*)src;
  *(int4*)&t[(r0 + 32) * 72 + cs] = *(const int4*)(src + 32 * 64);
  __syncthreads();
  int d = tid >> 2, c0 = (tid & 3) * 16;
  unsigned short vals[16];
#pragma unroll
  for (int j = 0; j < 16; j++) vals[j] = t[(c0 + j) * 72 + d];
  unsigned short* dst = vt + (h * 64 + d) * TK + kt * 64 + c0;
  *(int4*)dst = *(int4*)&vals[0];
  *(int4*)(dst + 8) = *(int4*)&vals[8];
}

// ---------------- fused flash attention (online softmax, fused rel-pos bias) ----------
// grid (33 q-tiles of 64, 8 heads), 256 threads (4 waves; wave w owns q rows w*16..w*16+15)

__global__ __launch_bounds__(256) void flash_attn(
    const unsigned short* __restrict__ qh, const unsigned short* __restrict__ kh,
    const unsigned short* __restrict__ vt,
    const int* __restrict__ rpe_a, const int* __restrict__ rpe_d,
    const float* __restrict__ emb_a, const float* __restrict__ emb_d,
    const float* __restrict__ maskp, unsigned short* __restrict__ o)
{
  __shared__ unsigned short Ks[64 * 72];
  __shared__ unsigned short Vs[64 * 72];
  __shared__ unsigned short Ps[64 * 72];
  __shared__ float pt[24 * 24];
  const int tid = threadIdx.x;
  const int lane = tid & 63, wave = tid >> 6;
  const int l15 = lane & 15, quad = lane >> 4;
  const int qt = blockIdx.x, h = blockIdx.y;
  const int q0 = qt * 64;
  const int qrow = q0 + wave * 16 + l15;
  const unsigned short* qbp = qh + (h * TP + qrow) * 64;
  bf16x8 qf0 = *(const bf16x8*)(qbp + quad * 8);
  bf16x8 qf1 = *(const bf16x8*)(qbp + 32 + quad * 8);
  f32x4 O[4];
#pragma unroll
  for (int nt = 0; nt < 4; nt++) O[nt] = (f32x4){0.f, 0.f, 0.f, 0.f};
  float mreg[4] = {-1e30f, -1e30f, -1e30f, -1e30f};
  float Lreg[4] = {0.f, 0.f, 0.f, 0.f};
  const int oq0 = q0 < 8 ? q0 : 8 + ((q0 - 8) >> 2);
  const int qe = q0 + 63;
  const int nq = (qe < 8 ? qe : 8 + ((qe - 8) >> 2)) - oq0 + 1;
  int myq[4];
#pragma unroll
  for (int r = 0; r < 4; r++) {
    int qr = q0 + wave * 16 + quad * 4 + r;
    myq[r] = (qr < 8 ? qr : 8 + ((qr - 8) >> 2)) - oq0;
  }
  const int sr = tid >> 3, sc = (tid & 7) * 8;
  const unsigned short* kgb = kh + (h * TP + sr) * 64 + sc;
  const unsigned short* vgb = vt + (h * 64 + sr) * TK + sc;

  for (int kt = 0; kt < 33; kt++) {
    const int kb = kt * 64;
    int4 kv0 = *(const int4*)(kgb + kb * 64);
    int4 kv1 = *(const int4*)(kgb + (kb + 32) * 64);
    int4 vv0 = *(const int4*)(vgb + kb);
    int4 vv1 = *(const int4*)(vgb + 32 * TK + kb);
    const int ok0 = kb < 8 ? kb : 8 + ((kb - 8) >> 2);
    const int ke = kb + 63;
    const int nk = (ke < 8 ? ke : 8 + ((ke - 8) >> 2)) - ok0 + 1;
    __syncthreads();  // prev iter's LDS reads complete
    *(int4*)&Ks[sr * 72 + sc] = kv0;
    *(int4*)&Ks[(sr + 32) * 72 + sc] = kv1;
    *(int4*)&Vs[sr * 72 + sc] = vv0;
    *(int4*)&Vs[(sr + 32) * 72 + sc] = vv1;
    for (int e = tid; e < nq * nk; e += 256) {
      int i = e / nk, j = e - i * nk;
      int oq = oq0 + i, ok = ok0 + j;
      float pv = 0.f;
      if (oq < NORIG && ok < NORIG) {
        int idx = oq * NORIG + ok;
        pv = (emb_a[rpe_a[idx] * NHEAD + h] + emb_d[rpe_d[idx] * NHEAD + h]) * 0.125f
             + maskp[idx];
      }
      pt[i * 24 + j] = pv;
    }
    __syncthreads();
    // S = Q K^T  (A=Q rows, B=K rows as Bt)
    f32x4 S[4];
#pragma unroll
    for (int nt = 0; nt < 4; nt++) S[nt] = (f32x4){0.f, 0.f, 0.f, 0.f};
#pragma unroll
    for (int nt = 0; nt < 4; nt++) {
      bf16x8 kf0 = *(const bf16x8*)&Ks[(nt * 16 + l15) * 72 + quad * 8];
      bf16x8 kf1 = *(const bf16x8*)&Ks[(nt * 16 + l15) * 72 + 32 + quad * 8];
      S[nt] = __builtin_amdgcn_mfma_f32_16x16x32_bf16(qf0, kf0, S[nt], 0, 0, 0);
      S[nt] = __builtin_amdgcn_mfma_f32_16x16x32_bf16(qf1, kf1, S[nt], 0, 0, 0);
    }
    int okp[4], colv[4];
#pragma unroll
    for (int nt = 0; nt < 4; nt++) {
      int c = kb + nt * 16 + l15;
      colv[nt] = c;
      okp[nt] = (c < 8 ? c : 8 + ((c - 8) >> 2)) - ok0;
    }
#pragma unroll
    for (int r = 0; r < 4; r++) {
      float a[4];
#pragma unroll
      for (int nt = 0; nt < 4; nt++)
        a[nt] = (colv[nt] < T_TOK) ? S[nt][r] * 0.125f + pt[myq[r] * 24 + okp[nt]] : -1e30f;
      float mr = fmaxf(fmaxf(a[0], a[1]), fmaxf(a[2], a[3]));
#pragma unroll
      for (int w = 1; w < 16; w <<= 1) mr = fmaxf(mr, __shfl_xor(mr, w, 64));
      float mn = fmaxf(mreg[r], mr);
      float alpha = __expf(mreg[r] - mn);
      mreg[r] = mn;
      float ps = 0.f;
#pragma unroll
      for (int nt = 0; nt < 4; nt++) {
        a[nt] = __expf(a[nt] - mn);
        ps += a[nt];
      }
#pragma unroll
      for (int w = 1; w < 16; w <<= 1) ps += __shfl_xor(ps, w, 64);
      Lreg[r] = Lreg[r] * alpha + ps;
#pragma unroll
      for (int nt = 0; nt < 4; nt++) O[nt][r] *= alpha;
      int pr = wave * 16 + quad * 4 + r;
#pragma unroll
      for (int nt = 0; nt < 4; nt++) Ps[pr * 72 + nt * 16 + l15] = f2bf(a[nt]);
    }
    __syncthreads();  // Ps visible
    // O += P V   (A=P rows, B=Vt rows)
    bf16x8 pa0 = *(const bf16x8*)&Ps[(wave * 16 + l15) * 72 + quad * 8];
    bf16x8 pa1 = *(const bf16x8*)&Ps[(wave * 16 + l15) * 72 + 32 + quad * 8];
#pragma unroll
    for (int nt = 0; nt < 4; nt++) {
      bf16x8 vb0 = *(const bf16x8*)&Vs[(nt * 16 + l15) * 72 + quad * 8];
      bf16x8 vb1 = *(const bf16x8*)&Vs[(nt * 16 + l15) * 72 + 32 + quad * 8];
      O[nt] = __builtin_amdgcn_mfma_f32_16x16x32_bf16(pa0, vb0, O[nt], 0, 0, 0);
      O[nt] = __builtin_amdgcn_mfma_f32_16x16x32_bf16(pa1, vb1, O[nt], 0, 0, 0);
    }
  }
#pragma unroll
  for (int r = 0; r < 4; r++) {
    float inv = 1.f / Lreg[r];
    int orow = q0 + wave * 16 + quad * 4 + r;
    unsigned short* op = o + orow * HIDDEN + h * ADIM;
#pragma unroll
    for (int nt = 0; nt < 4; nt++) op[nt * 16 + l15] = f2bf(O[nt][r] * inv);
  }
}

// ---------------- residual + LN, fp32 in place + bf16 mirror ----------------

__global__ __launch_bounds__(256) void ln_residual(
    float* __restrict__ x, const float* __restrict__ delta,
    const float* __restrict__ g, const float* __restrict__ b,
    unsigned short* __restrict__ xb)
{
  __shared__ float sb[4];
  int row = blockIdx.x;
  int j0 = threadIdx.x, j1 = threadIdx.x + 256;
  int base = row * HIDDEN;
  float v0 = x[base + j0] + delta[base + j0];
  float v1 = x[base + j1] + delta[base + j1];
  float s1 = blockReduceSum(v0 + v1, sb);
  float s2 = blockReduceSum(v0 * v0 + v1 * v1, sb);
  float m = s1 * (1.0f / HIDDEN);
  float var = s2 * (1.0f / HIDDEN) - m * m;
  float inv = rsqrtf(var + 1e-5f);
  float y0 = (v0 - m) * inv * g[j0] + b[j0];
  float y1 = (v1 - m) * inv * g[j1] + b[j1];
  x[base + j0] = y0;
  x[base + j1] = y1;
  xb[base + j0] = f2bf(y0);
  xb[base + j1] = f2bf(y1);
}

__global__ __launch_bounds__(256) void copy_out(
    const float4* __restrict__ src, float4* __restrict__ dst, int n4)
{
  int i = blockIdx.x * 256 + threadIdx.x;
  if (i < n4) dst[i] = src[i];
}

// ---------------- driver ----------------

extern "C" void kernel_launch(void* const* d_in, const int* in_sizes, int n_in,
                              void* d_out, int out_size, void* d_ws, size_t ws_size,
                              hipStream_t stream) {
  const float* obj   = (const float*)d_in[0];
  const float* st0   = (const float*)d_in[2];
  const int*   rpe_a = (const int*)d_in[3];
  const int*   rpe_d = (const int*)d_in[4];
  const float* mask  = (const float*)d_in[5];
  const float* Wpg = (const float*)d_in[6];  const float* bpg = (const float*)d_in[7];
  const float* pg_g = (const float*)d_in[8]; const float* pg_b = (const float*)d_in[9];
  const float* Wps = (const float*)d_in[10]; const float* bps = (const float*)d_in[11];
  const float* ps_g = (const float*)d_in[12];const float* ps_b = (const float*)d_in[13];
  const float* emb_a = (const float*)d_in[14];
  const float* emb_d = (const float*)d_in[15];
  const float* Wq = (const float*)d_in[16]; const float* bq = (const float*)d_in[17];
  const float* Wk = (const float*)d_in[18]; const float* bk = (const float*)d_in[19];
  const float* Wv = (const float*)d_in[20]; const float* bv = (const float*)d_in[21];
  const float* Wo = (const float*)d_in[22]; const float* bo = (const float*)d_in[23];
  const float* W1 = (const float*)d_in[24]; const float* b1 = (const float*)d_in[25];
  const float* W2 = (const float*)d_in[26]; const float* b2 = (const float*)d_in[27];
  const float* ln1_g = (const float*)d_in[28]; const float* ln1_b = (const float*)d_in[29];
  const float* ln2_g = (const float*)d_in[30]; const float* ln2_b = (const float*)d_in[31];

  char* p = (char*)d_ws;
  auto alloc = [&](size_t bytes) { char* q = p; p += (bytes + 255) & ~(size_t)255; return q; };
  float*          x     = (float*)alloc((size_t)T_TOK * HIDDEN * 4);
  float*          delta = (float*)alloc((size_t)TP * HIDDEN * 4);
  unsigned short* xb    = (unsigned short*)alloc((size_t)TP * HIDDEN * 2);
  unsigned short* qhb   = (unsigned short*)alloc((size_t)NHEAD * TP * ADIM * 2);
  unsigned short* khb   = (unsigned short*)alloc((size_t)NHEAD * TP * ADIM * 2);
  unsigned short* vhb   = (unsigned short*)alloc((size_t)NHEAD * TP * ADIM * 2);
  unsigned short* vtb   = (unsigned short*)alloc((size_t)NHEAD * ADIM * TK * 2);
  unsigned short* ob    = (unsigned short*)alloc((size_t)TP * HIDDEN * 2);
  unsigned short* hb    = (unsigned short*)alloc((size_t)TP * FFDIM * 2);
  unsigned short* Wqkvt = (unsigned short*)alloc((size_t)1536 * 512 * 2);
  unsigned short* Wot   = (unsigned short*)alloc((size_t)512 * 512 * 2);
  unsigned short* W1t   = (unsigned short*)alloc((size_t)2048 * 512 * 2);
  unsigned short* W2t   = (unsigned short*)alloc((size_t)512 * 2048 * 2);
  if ((size_t)(p - (char*)d_ws) > ws_size) return;

  float* out = (float*)d_out;

  embed_kernel<<<T_TOK, 256, 0, stream>>>(obj, st0, Wpg, bpg, pg_g, pg_b,
                                          Wps, bps, ps_g, ps_b, x, xb);
  padzero<<<((TP - T_TOK) * HIDDEN + 255) / 256, 256, 0, stream>>>(xb);

  for (int l = 0; l < NLAYER; l++) {
    wtrans<<<768, 256, 0, stream>>>(
        Wq + l * 512 * 512, Wk + l * 512 * 512, Wv + l * 512 * 512,
        Wo + l * 512 * 512, W1 + l * 512 * 2048, W2 + l * 2048 * 512,
        Wqkvt, Wot, W1t, W2t);
    // QKV (N=1536 packed)
    gemm_bt<<<dim3(12, 17), 256, 0, stream>>>(
        xb, HIDDEN, Wqkvt, HIDDEN, HIDDEN, 0,
        bq + l * 512, bk + l * 512, bv + l * 512, qhb, khb, vhb, nullptr, 0);
    vt_trans<<<dim3(33, 8), 256, 0, stream>>>(vhb, vtb);
    flash_attn<<<dim3(33, 8), 256, 0, stream>>>(
        qhb, khb, vtb, rpe_a, rpe_d, emb_a, emb_d, mask, ob);
    // O projection -> delta (fp32)
    gemm_bt<<<dim3(4, 17), 256, 0, stream>>>(
        ob, HIDDEN, Wot, HIDDEN, HIDDEN, 1,
        bo + l * 512, nullptr, nullptr, nullptr, nullptr, nullptr, delta, HIDDEN);
    ln_residual<<<T_TOK, 256, 0, stream>>>(x, delta, ln1_g + l * 512, ln1_b + l * 512, xb);
    // FFN1 -> hb (bf16, leaky)
    gemm_bt<<<dim3(16, 17), 256, 0, stream>>>(
        xb, HIDDEN, W1t, HIDDEN, HIDDEN, 2,
        b1 + l * 2048, nullptr, nullptr, hb, nullptr, nullptr, nullptr, FFDIM);
    // FFN2 -> delta (fp32)
    gemm_bt<<<dim3(4, 17), 256, 0, stream>>>(
        hb, FFDIM, W2t, FFDIM, FFDIM, 1,
        b2 + l * 512, nullptr, nullptr, nullptr, nullptr, nullptr, delta, HIDDEN);
    ln_residual<<<T_TOK, 256, 0, stream>>>(x, delta, ln2_g + l * 512, ln2_b + l * 512, xb);
  }

  int n4 = T_TOK * HIDDEN / 4;
  copy_out<<<(n4 + 255) / 256, 256, 0, stream>>>((const float4*)x, (float4*)out, n4);
}

// Round 3
// 1189.478 us; speedup vs baseline: 17.3699x; 1.5566x over previous
//
#include <hip/hip_runtime.h>
#include <math.h>

#define T_TOK 2056
#define TP 2176      // 17*128  M-padded rows
#define TK 2112      // 33*64   KV-padded rows
#define HIDDEN 512
#define NHEAD 8
#define ADIM 64
#define FFDIM 2048
#define NLAYER 6
#define NORIG 520
#define NOBJ 8
#define NSPLIT 4     // flash KV splits and GEMM K-splits

typedef float f32x4 __attribute__((ext_vector_type(4)));
typedef __attribute__((__ext_vector_type__(8))) __bf16 bf16x8;

__device__ __forceinline__ unsigned short f2bf(float f) {
  unsigned int u = __float_as_uint(f);
  u += 0x7FFFu + ((u >> 16) & 1u);
  return (unsigned short)(u >> 16);
}
__device__ __forceinline__ float bf2f(unsigned short u) {
  return __uint_as_float(((unsigned int)u) << 16);
}

// ---------------- block reduction helpers (256 threads = 4 waves) ----------------

__device__ inline float blockReduceSum(float v, float* sb) {
#pragma unroll
  for (int off = 32; off > 0; off >>= 1) v += __shfl_down(v, off, 64);
  int wid = threadIdx.x >> 6;
  __syncthreads();
  if ((threadIdx.x & 63) == 0) sb[wid] = v;
  __syncthreads();
  return sb[0] + sb[1] + sb[2] + sb[3];
}

// ---------------- token embedding: project + LN + leaky_relu (fp32 + bf16 mirror) ----

__global__ __launch_bounds__(256) void embed_kernel(
    const float* __restrict__ obj, const float* __restrict__ st0,
    const float* __restrict__ Wpg, const float* __restrict__ bpg,
    const float* __restrict__ pg_g, const float* __restrict__ pg_b,
    const float* __restrict__ Wps, const float* __restrict__ bps,
    const float* __restrict__ ps_g, const float* __restrict__ ps_b,
    float* __restrict__ x, unsigned short* __restrict__ xb)
{
  __shared__ float sb[4];
  int t = blockIdx.x;
  int j0 = threadIdx.x, j1 = threadIdx.x + 256;
  float a0, a1;
  const float *g, *b;
  if (t < NOBJ) {
    a0 = bpg[j0]; a1 = bpg[j1];
    const float* in = obj + t * 100;
    for (int i = 0; i < 100; i++) {
      float w = in[i];
      a0 += w * Wpg[i * HIDDEN + j0];
      a1 += w * Wpg[i * HIDDEN + j1];
    }
    g = pg_g; b = pg_b;
  } else {
    int tt = t - NOBJ, s = tt >> 2, p = tt & 3;
    float c0 = st0[s * 10 + p * 2], c1 = st0[s * 10 + p * 2 + 1];
    a0 = bps[j0] + c0 * Wps[j0] + c1 * Wps[HIDDEN + j0];
    a1 = bps[j1] + c0 * Wps[j1] + c1 * Wps[HIDDEN + j1];
    g = ps_g; b = ps_b;
  }
  float s1 = blockReduceSum(a0 + a1, sb);
  float s2 = blockReduceSum(a0 * a0 + a1 * a1, sb);
  float m = s1 * (1.0f / HIDDEN);
  float var = s2 * (1.0f / HIDDEN) - m * m;
  float inv = rsqrtf(var + 1e-5f);
  float y0 = (a0 - m) * inv * g[j0] + b[j0];
  float y1 = (a1 - m) * inv * g[j1] + b[j1];
  y0 = y0 >= 0.f ? y0 : 0.01f * y0;
  y1 = y1 >= 0.f ? y1 : 0.01f * y1;
  x[t * HIDDEN + j0] = y0;
  x[t * HIDDEN + j1] = y1;
  xb[t * HIDDEN + j0] = f2bf(y0);
  xb[t * HIDDEN + j1] = f2bf(y1);
}

// zero xb pad rows (re-run every launch; ws is re-poisoned)
__global__ __launch_bounds__(256) void padzero(unsigned short* __restrict__ xb) {
  int i = blockIdx.x * 256 + threadIdx.x;
  if (i < (TP - T_TOK) * HIDDEN) xb[T_TOK * HIDDEN + i] = 0;
}

// ---------------- precompute rel-pos bias table: posb[h][520][520] (bf16) ----------
// posb = (emb_a[rpe_a]+emb_d[rpe_d]) * 0.125 + mask   (layer-invariant)

__global__ __launch_bounds__(256) void posbuild(
    const int* __restrict__ rpe_a, const int* __restrict__ rpe_d,
    const float* __restrict__ emb_a, const float* __restrict__ emb_d,
    const float* __restrict__ mask, unsigned short* __restrict__ posb)
{
  int i = blockIdx.x;
  for (int j = threadIdx.x; j < NORIG; j += 256) {
    int a = rpe_a[i * NORIG + j];
    int d = rpe_d[i * NORIG + j];
    float mk = mask[i * NORIG + j];
#pragma unroll
    for (int h = 0; h < NHEAD; h++) {
      float v = (emb_a[a * NHEAD + h] + emb_d[d * NHEAD + h]) * 0.125f + mk;
      posb[(h * NORIG + i) * NORIG + j] = f2bf(v);
    }
  }
}

// ---------------- weight transpose+convert: fp32 [K][N] -> bf16 [N][K] ----------------

__global__ __launch_bounds__(256) void wtrans(
    const float* __restrict__ Wq, const float* __restrict__ Wk, const float* __restrict__ Wv,
    const float* __restrict__ Wo, const float* __restrict__ W1, const float* __restrict__ W2,
    unsigned short* __restrict__ Wqkvt, unsigned short* __restrict__ Wot,
    unsigned short* __restrict__ W1t, unsigned short* __restrict__ W2t)
{
  __shared__ float t[64 * 65];
  int b = blockIdx.x;
  const float* src; unsigned short* dst; int N, K, tk, tn;
  if (b < 192) {
    int m = b >> 6, bb = b & 63;
    src = m == 0 ? Wq : m == 1 ? Wk : Wv;
    dst = Wqkvt + m * 512 * 512;
    K = 512; N = 512; tk = bb & 7; tn = bb >> 3;
  } else if (b < 256) {
    int bb = b - 192; src = Wo; dst = Wot; K = 512; N = 512; tk = bb & 7; tn = bb >> 3;
  } else if (b < 512) {
    int bb = b - 256; src = W1; dst = W1t; K = 512; N = 2048; tk = bb & 7; tn = bb >> 3;
  } else {
    int bb = b - 512; src = W2; dst = W2t; K = 2048; N = 512; tk = bb & 31; tn = bb >> 5;
  }
  int k0 = tk * 64, n0 = tn * 64;
  int tid = threadIdx.x;
  int r = tid >> 2, c0 = (tid & 3) * 16;
  const float* sp = src + (k0 + r) * N + n0 + c0;
#pragma unroll
  for (int q = 0; q < 4; q++) {
    float4 f = *(const float4*)(sp + q * 4);
    t[r * 65 + c0 + q * 4 + 0] = f.x;
    t[r * 65 + c0 + q * 4 + 1] = f.y;
    t[r * 65 + c0 + q * 4 + 2] = f.z;
    t[r * 65 + c0 + q * 4 + 3] = f.w;
  }
  __syncthreads();
  unsigned short vals[16];
#pragma unroll
  for (int j = 0; j < 16; j++) vals[j] = f2bf(t[(c0 + j) * 65 + r]);
  unsigned short* dp = dst + (n0 + r) * K + k0 + c0;
  *(int4*)dp = *(int4*)&vals[0];
  *(int4*)(dp + 8) = *(int4*)&vals[8];
}

// ---------------- MFMA GEMM: C[M=2176][N] = A[.][K] * Bt[N][K]^T, bf16 in / fp32 acc ----
// 128x128 tile, 4 waves each 64x64 (4x4 of 16x16x32). LDS stride 56.
// mode 0: +bias(seg) -> scatter bf16 to qh/kh/vh [head][TP][64]
// mode 1: split-K partial (gridDim.z splits) -> fp32 df[z][TP][ldc]  (NO bias)
// mode 2: +bias, leaky -> bf16 d0

__global__ __launch_bounds__(256) void gemm_bt(
    const unsigned short* __restrict__ A, int lda,
    const unsigned short* __restrict__ Bt, int ldb, int K, int mode,
    const float* __restrict__ b0, const float* __restrict__ b1, const float* __restrict__ b2,
    unsigned short* __restrict__ d0, unsigned short* __restrict__ d1, unsigned short* __restrict__ d2,
    float* __restrict__ df, int ldc)
{
  __shared__ unsigned short As[128 * 56];
  __shared__ unsigned short Bs[128 * 56];
  const int tid = threadIdx.x;
  const int lane = tid & 63, wave = tid >> 6;
  const int l15 = lane & 15, quad = lane >> 4;
  const int rowBase = blockIdx.y * 128, colBase = blockIdx.x * 128;
  const int mw = (wave >> 1) * 64, nw = (wave & 1) * 64;
  const int sr = tid >> 2, sc = (tid & 3) * 8;
  const int zz = blockIdx.z;
  const int kLen = K / gridDim.z;
  const int kb0 = zz * kLen;
  const unsigned short* Ag0 = A + (rowBase + sr) * lda + sc;
  const unsigned short* Ag1 = Ag0 + 64 * lda;
  const unsigned short* Bg0 = Bt + (colBase + sr) * ldb + sc;
  const unsigned short* Bg1 = Bg0 + 64 * ldb;
  f32x4 acc[4][4];
#pragma unroll
  for (int i = 0; i < 4; i++)
#pragma unroll
    for (int j = 0; j < 4; j++) acc[i][j] = (f32x4){0.f, 0.f, 0.f, 0.f};

  for (int kb = kb0; kb < kb0 + kLen; kb += 32) {
    int4 a0 = *(const int4*)(Ag0 + kb);
    int4 a1 = *(const int4*)(Ag1 + kb);
    int4 g0 = *(const int4*)(Bg0 + kb);
    int4 g1 = *(const int4*)(Bg1 + kb);
    __syncthreads();
    *(int4*)&As[sr * 56 + sc] = a0;
    *(int4*)&As[(sr + 64) * 56 + sc] = a1;
    *(int4*)&Bs[sr * 56 + sc] = g0;
    *(int4*)&Bs[(sr + 64) * 56 + sc] = g1;
    __syncthreads();
    bf16x8 af[4], bfr[4];
#pragma unroll
    for (int mt = 0; mt < 4; mt++)
      af[mt] = *(const bf16x8*)&As[(mw + mt * 16 + l15) * 56 + quad * 8];
#pragma unroll
    for (int nt = 0; nt < 4; nt++)
      bfr[nt] = *(const bf16x8*)&Bs[(nw + nt * 16 + l15) * 56 + quad * 8];
#pragma unroll
    for (int mt = 0; mt < 4; mt++)
#pragma unroll
      for (int nt = 0; nt < 4; nt++)
        acc[mt][nt] = __builtin_amdgcn_mfma_f32_16x16x32_bf16(af[mt], bfr[nt], acc[mt][nt], 0, 0, 0);
  }

  float* dfz = df + (size_t)zz * TP * ldc;
#pragma unroll
  for (int mt = 0; mt < 4; mt++) {
#pragma unroll
    for (int nt = 0; nt < 4; nt++) {
#pragma unroll
      for (int r = 0; r < 4; r++) {
        int row = rowBase + mw + mt * 16 + quad * 4 + r;
        int col = colBase + nw + nt * 16 + l15;
        float v = acc[mt][nt][r];
        if (mode == 0) {
          int seg = col >> 9, cc = col & 511;
          const float* bs = seg == 0 ? b0 : seg == 1 ? b1 : b2;
          unsigned short* dst = seg == 0 ? d0 : seg == 1 ? d1 : d2;
          int hd = cc >> 6, d = cc & 63;
          dst[(hd * TP + row) * 64 + d] = f2bf(v + bs[cc]);
        } else if (mode == 1) {
          dfz[row * ldc + col] = v;
        } else {
          float t = v + b0[col];
          t = t >= 0.f ? t : 0.01f * t;
          d0[row * ldc + col] = f2bf(t);
        }
      }
    }
  }
}

// ---------------- V transpose: vh [h][TP][64] -> vt [h][64][TK] ----------------

__global__ __launch_bounds__(256) void vt_trans(
    const unsigned short* __restrict__ vh, unsigned short* __restrict__ vt)
{
  __shared__ unsigned short t[64 * 72];
  int kt = blockIdx.x, h = blockIdx.y;
  int tid = threadIdx.x;
  int r0 = tid >> 3, cs = (tid & 7) * 8;
  const unsigned short* src = vh + (h * TP + kt * 64 + r0) * 64 + cs;
  *(int4*)&t[r0 * 72 + cs] = *(const int4*)src;
  *(int4*)&t[(r0 + 32) * 72 + cs] = *(const int4*)(src + 32 * 64);
  __syncthreads();
  int d = tid >> 2, c0 = (tid & 3) * 16;
  unsigned short vals[16];
#pragma unroll
  for (int j = 0; j < 16; j++) vals[j] = t[(c0 + j) * 72 + d];
  unsigned short* dst = vt + (h * 64 + d) * TK + kt * 64 + c0;
  *(int4*)dst = *(int4*)&vals[0];
  *(int4*)(dst + 8) = *(int4*)&vals[8];
}

// ---------------- split-KV flash attention (online softmax, precomputed bias) -------
// grid (33 q-tiles, 8 heads, NSPLIT kv-splits); 256 threads (4 waves x 16 q-rows).
// Emits unnormalized Opart + (m,l) per row; flash_merge combines.

__global__ __launch_bounds__(256) void flash_attn(
    const unsigned short* __restrict__ qh, const unsigned short* __restrict__ kh,
    const unsigned short* __restrict__ vt, const unsigned short* __restrict__ posb,
    float* __restrict__ Opart, float* __restrict__ ml)
{
  __shared__ unsigned short Ks[64 * 72];
  __shared__ unsigned short Vs[64 * 72];
  __shared__ unsigned short Ps[64 * 72];
  __shared__ float pt[24 * 24];
  const int tid = threadIdx.x;
  const int lane = tid & 63, wave = tid >> 6;
  const int l15 = lane & 15, quad = lane >> 4;
  const int qt = blockIdx.x, h = blockIdx.y, z = blockIdx.z;
  const int q0 = qt * 64;
  const int qrow = q0 + wave * 16 + l15;
  const unsigned short* qbp = qh + (h * TP + qrow) * 64;
  bf16x8 qf0 = *(const bf16x8*)(qbp + quad * 8);
  bf16x8 qf1 = *(const bf16x8*)(qbp + 32 + quad * 8);
  f32x4 O[4];
#pragma unroll
  for (int nt = 0; nt < 4; nt++) O[nt] = (f32x4){0.f, 0.f, 0.f, 0.f};
  float mreg[4] = {-1e30f, -1e30f, -1e30f, -1e30f};
  float Lreg[4] = {0.f, 0.f, 0.f, 0.f};
  const int oq0 = q0 < 8 ? q0 : 8 + ((q0 - 8) >> 2);
  const int qe = min(q0 + 63, T_TOK - 1);
  const int nq = (qe < 8 ? qe : 8 + ((qe - 8) >> 2)) - oq0 + 1;
  int myq[4];
#pragma unroll
  for (int r = 0; r < 4; r++) {
    int qr = q0 + wave * 16 + quad * 4 + r;
    myq[r] = (qr < 8 ? qr : 8 + ((qr - 8) >> 2)) - oq0;
  }
  const int sr = tid >> 3, sc = (tid & 7) * 8;
  const unsigned short* kgb = kh + (h * TP + sr) * 64 + sc;
  const unsigned short* vgb = vt + (h * 64 + sr) * TK + sc;
  const int ptrow = tid >> 3, ptc0 = (tid & 7) * 3;

  const int kt0 = z * 9, kt1 = min(33, kt0 + 9);
  for (int kt = kt0; kt < kt1; kt++) {
    const int kb = kt * 64;
    int4 kv0 = *(const int4*)(kgb + kb * 64);
    int4 kv1 = *(const int4*)(kgb + (kb + 32) * 64);
    int4 vv0 = *(const int4*)(vgb + kb);
    int4 vv1 = *(const int4*)(vgb + 32 * TK + kb);
    const int ok0 = kb < 8 ? kb : 8 + ((kb - 8) >> 2);
    const int ke = min(kb + 63, T_TOK - 1);
    const int nk = (ke < 8 ? ke : 8 + ((ke - 8) >> 2)) - ok0 + 1;
    __syncthreads();  // prev iter's LDS reads complete
    *(int4*)&Ks[sr * 72 + sc] = kv0;
    *(int4*)&Ks[(sr + 32) * 72 + sc] = kv1;
    *(int4*)&Vs[sr * 72 + sc] = vv0;
    *(int4*)&Vs[(sr + 32) * 72 + sc] = vv1;
    if (ptrow < 24) {
      const unsigned short* prow = posb + (h * NORIG + oq0 + ptrow) * NORIG + ok0;
      bool rok = ptrow < nq;
#pragma unroll
      for (int c = 0; c < 3; c++) {
        int col = ptc0 + c;
        pt[ptrow * 24 + col] = (rok && col < nk) ? bf2f(prow[col]) : 0.f;
      }
    }
    __syncthreads();
    // S = Q K^T
    f32x4 S[4];
#pragma unroll
    for (int nt = 0; nt < 4; nt++) S[nt] = (f32x4){0.f, 0.f, 0.f, 0.f};
#pragma unroll
    for (int nt = 0; nt < 4; nt++) {
      bf16x8 kf0 = *(const bf16x8*)&Ks[(nt * 16 + l15) * 72 + quad * 8];
      bf16x8 kf1 = *(const bf16x8*)&Ks[(nt * 16 + l15) * 72 + 32 + quad * 8];
      S[nt] = __builtin_amdgcn_mfma_f32_16x16x32_bf16(qf0, kf0, S[nt], 0, 0, 0);
      S[nt] = __builtin_amdgcn_mfma_f32_16x16x32_bf16(qf1, kf1, S[nt], 0, 0, 0);
    }
    int okp[4], colv[4];
#pragma unroll
    for (int nt = 0; nt < 4; nt++) {
      int c = kb + nt * 16 + l15;
      colv[nt] = c;
      okp[nt] = (c < 8 ? c : 8 + ((c - 8) >> 2)) - ok0;
    }
#pragma unroll
    for (int r = 0; r < 4; r++) {
      float a[4];
#pragma unroll
      for (int nt = 0; nt < 4; nt++)
        a[nt] = (colv[nt] < T_TOK) ? S[nt][r] * 0.125f + pt[myq[r] * 24 + okp[nt]] : -1e30f;
      float mr = fmaxf(fmaxf(a[0], a[1]), fmaxf(a[2], a[3]));
#pragma unroll
      for (int w = 1; w < 16; w <<= 1) mr = fmaxf(mr, __shfl_xor(mr, w, 64));
      float mn = fmaxf(mreg[r], mr);
      float alpha = __expf(mreg[r] - mn);
      mreg[r] = mn;
      float ps = 0.f;
#pragma unroll
      for (int nt = 0; nt < 4; nt++) {
        a[nt] = __expf(a[nt] - mn);
        ps += a[nt];
      }
#pragma unroll
      for (int w = 1; w < 16; w <<= 1) ps += __shfl_xor(ps, w, 64);
      Lreg[r] = Lreg[r] * alpha + ps;
#pragma unroll
      for (int nt = 0; nt < 4; nt++) O[nt][r] *= alpha;
      int pr = wave * 16 + quad * 4 + r;
#pragma unroll
      for (int nt = 0; nt < 4; nt++) Ps[pr * 72 + nt * 16 + l15] = f2bf(a[nt]);
    }
    __syncthreads();  // Ps visible
    // O += P V
    bf16x8 pa0 = *(const bf16x8*)&Ps[(wave * 16 + l15) * 72 + quad * 8];
    bf16x8 pa1 = *(const bf16x8*)&Ps[(wave * 16 + l15) * 72 + 32 + quad * 8];
#pragma unroll
    for (int nt = 0; nt < 4; nt++) {
      bf16x8 vb0 = *(const bf16x8*)&Vs[(nt * 16 + l15) * 72 + quad * 8];
      bf16x8 vb1 = *(const bf16x8*)&Vs[(nt * 16 + l15) * 72 + 32 + quad * 8];
      O[nt] = __builtin_amdgcn_mfma_f32_16x16x32_bf16(pa0, vb0, O[nt], 0, 0, 0);
      O[nt] = __builtin_amdgcn_mfma_f32_16x16x32_bf16(pa1, vb1, O[nt], 0, 0, 0);
    }
  }
#pragma unroll
  for (int r = 0; r < 4; r++) {
    int orow = q0 + wave * 16 + quad * 4 + r;
    size_t base = ((size_t)(z * NHEAD + h) * TK + orow);
    if (l15 == 0) {
      ml[base * 2] = mreg[r];
      ml[base * 2 + 1] = Lreg[r];
    }
#pragma unroll
    for (int nt = 0; nt < 4; nt++)
      Opart[base * 64 + nt * 16 + l15] = O[nt][r];
  }
}

// ---------------- merge flash splits -> ob (bf16 [T][512]) ----------------

__global__ __launch_bounds__(256) void flash_merge(
    const float* __restrict__ Opart, const float* __restrict__ ml,
    unsigned short* __restrict__ ob)
{
  int idx = blockIdx.x * 256 + threadIdx.x;
  if (idx >= T_TOK * HIDDEN) return;
  int row = idx >> 9, c = idx & 511;
  int h = c >> 6, d = c & 63;
  float M = -1e30f;
  float mv[NSPLIT], lv[NSPLIT];
#pragma unroll
  for (int s = 0; s < NSPLIT; s++) {
    size_t base = ((size_t)(s * NHEAD + h) * TK + row);
    mv[s] = ml[base * 2];
    lv[s] = ml[base * 2 + 1];
    M = fmaxf(M, mv[s]);
  }
  float num = 0.f, den = 0.f;
#pragma unroll
  for (int s = 0; s < NSPLIT; s++) {
    float w = __expf(mv[s] - M);
    den += w * lv[s];
    num += w * Opart[((size_t)(s * NHEAD + h) * TK + row) * 64 + d];
  }
  ob[idx] = f2bf(num / den);
}

// ---------------- residual + bias + 4-way split-K sum + LN, fp32 + bf16 mirror -------

__global__ __launch_bounds__(256) void ln_residual4(
    float* __restrict__ x, const float* __restrict__ parts,
    const float* __restrict__ bias,
    const float* __restrict__ g, const float* __restrict__ b,
    unsigned short* __restrict__ xb)
{
  __shared__ float sb[4];
  int row = blockIdx.x;
  int j0 = threadIdx.x, j1 = threadIdx.x + 256;
  int base = row * HIDDEN;
  const size_t ss = (size_t)TP * HIDDEN;
  float v0 = x[base + j0] + bias[j0] + parts[base + j0] + parts[ss + base + j0]
           + parts[2 * ss + base + j0] + parts[3 * ss + base + j0];
  float v1 = x[base + j1] + bias[j1] + parts[base + j1] + parts[ss + base + j1]
           + parts[2 * ss + base + j1] + parts[3 * ss + base + j1];
  float s1 = blockReduceSum(v0 + v1, sb);
  float s2 = blockReduceSum(v0 * v0 + v1 * v1, sb);
  float m = s1 * (1.0f / HIDDEN);
  float var = s2 * (1.0f / HIDDEN) - m * m;
  float inv = rsqrtf(var + 1e-5f);
  float y0 = (v0 - m) * inv * g[j0] + b[j0];
  float y1 = (v1 - m) * inv * g[j1] + b[j1];
  x[base + j0] = y0;
  x[base + j1] = y1;
  xb[base + j0] = f2bf(y0);
  xb[base + j1] = f2bf(y1);
}

__global__ __launch_bounds__(256) void copy_out(
    const float4* __restrict__ src, float4* __restrict__ dst, int n4)
{
  int i = blockIdx.x * 256 + threadIdx.x;
  if (i < n4) dst[i] = src[i];
}

// ---------------- driver ----------------

extern "C" void kernel_launch(void* const* d_in, const int* in_sizes, int n_in,
                              void* d_out, int out_size, void* d_ws, size_t ws_size,
                              hipStream_t stream) {
  const float* obj   = (const float*)d_in[0];
  const float* st0   = (const float*)d_in[2];
  const int*   rpe_a = (const int*)d_in[3];
  const int*   rpe_d = (const int*)d_in[4];
  const float* mask  = (const float*)d_in[5];
  const float* Wpg = (const float*)d_in[6];  const float* bpg = (const float*)d_in[7];
  const float* pg_g = (const float*)d_in[8]; const float* pg_b = (const float*)d_in[9];
  const float* Wps = (const float*)d_in[10]; const float* bps = (const float*)d_in[11];
  const float* ps_g = (const float*)d_in[12];const float* ps_b = (const float*)d_in[13];
  const float* emb_a = (const float*)d_in[14];
  const float* emb_d = (const float*)d_in[15];
  const float* Wq = (const float*)d_in[16]; const float* bq = (const float*)d_in[17];
  const float* Wk = (const float*)d_in[18]; const float* bk = (const float*)d_in[19];
  const float* Wv = (const float*)d_in[20]; const float* bv = (const float*)d_in[21];
  const float* Wo = (const float*)d_in[22]; const float* bo = (const float*)d_in[23];
  const float* W1 = (const float*)d_in[24]; const float* b1 = (const float*)d_in[25];
  const float* W2 = (const float*)d_in[26]; const float* b2 = (const float*)d_in[27];
  const float* ln1_g = (const float*)d_in[28]; const float* ln1_b = (const float*)d_in[29];
  const float* ln2_g = (const float*)d_in[30]; const float* ln2_b = (const float*)d_in[31];

  // ---- workspace layout (phase-disjoint unions; total 46.04 MB) ----
  char* p = (char*)d_ws;
  auto alloc = [&](size_t bytes) { char* q = p; p += (bytes + 255) & ~(size_t)255; return q; };
  float*          x      = (float*)alloc((size_t)T_TOK * HIDDEN * 4);
  unsigned short* xb     = (unsigned short*)alloc((size_t)TP * HIDDEN * 2);
  // union1: {qhb,khb,vhb,vtb} (attention phase) | hb (FFN phase)
  char*           u1     = (char*)alloc((size_t)TP * FFDIM * 2);  // 8,912,896 B
  unsigned short* qhb    = (unsigned short*)u1;
  unsigned short* khb    = qhb + (size_t)NHEAD * TP * ADIM;
  unsigned short* vhb    = khb + (size_t)NHEAD * TP * ADIM;
  unsigned short* vtb    = vhb + (size_t)NHEAD * TP * ADIM;
  unsigned short* hb     = (unsigned short*)u1;
  unsigned short* ob     = (unsigned short*)alloc((size_t)TP * HIDDEN * 2);
  // union2: {Opart+ml} (flash) | parts (split-K GEMM)
  char*           u2     = (char*)alloc((size_t)NSPLIT * NHEAD * TK * ADIM * 4 + (size_t)NSPLIT * NHEAD * TK * 2 * 4);
  float*          Opart  = (float*)u2;
  float*          mlb    = Opart + (size_t)NSPLIT * NHEAD * TK * ADIM;
  float*          parts  = (float*)u2;
  unsigned short* posb   = (unsigned short*)alloc((size_t)NHEAD * NORIG * NORIG * 2);
  unsigned short* Wqkvt  = (unsigned short*)alloc((size_t)1536 * 512 * 2);
  unsigned short* Wot    = (unsigned short*)alloc((size_t)512 * 512 * 2);
  unsigned short* W1t    = (unsigned short*)alloc((size_t)2048 * 512 * 2);
  unsigned short* W2t    = (unsigned short*)alloc((size_t)512 * 2048 * 2);
  if ((size_t)(p - (char*)d_ws) > ws_size) return;

  float* out = (float*)d_out;

  embed_kernel<<<T_TOK, 256, 0, stream>>>(obj, st0, Wpg, bpg, pg_g, pg_b,
                                          Wps, bps, ps_g, ps_b, x, xb);
  padzero<<<((TP - T_TOK) * HIDDEN + 255) / 256, 256, 0, stream>>>(xb);
  posbuild<<<NORIG, 256, 0, stream>>>(rpe_a, rpe_d, emb_a, emb_d, mask, posb);

  for (int l = 0; l < NLAYER; l++) {
    wtrans<<<768, 256, 0, stream>>>(
        Wq + l * 512 * 512, Wk + l * 512 * 512, Wv + l * 512 * 512,
        Wo + l * 512 * 512, W1 + l * 512 * 2048, W2 + l * 2048 * 512,
        Wqkvt, Wot, W1t, W2t);
    // QKV (N=1536 packed)
    gemm_bt<<<dim3(12, 17, 1), 256, 0, stream>>>(
        xb, HIDDEN, Wqkvt, HIDDEN, HIDDEN, 0,
        bq + l * 512, bk + l * 512, bv + l * 512, qhb, khb, vhb, nullptr, 0);
    vt_trans<<<dim3(33, 8), 256, 0, stream>>>(vhb, vtb);
    flash_attn<<<dim3(33, 8, NSPLIT), 256, 0, stream>>>(
        qhb, khb, vtb, posb, Opart, mlb);
    flash_merge<<<(T_TOK * HIDDEN + 255) / 256, 256, 0, stream>>>(Opart, mlb, ob);
    // O projection: split-K(4) -> parts, reduce fused into LN
    gemm_bt<<<dim3(4, 17, NSPLIT), 256, 0, stream>>>(
        ob, HIDDEN, Wot, HIDDEN, HIDDEN, 1,
        nullptr, nullptr, nullptr, nullptr, nullptr, nullptr, parts, HIDDEN);
    ln_residual4<<<T_TOK, 256, 0, stream>>>(x, parts, bo + l * 512,
                                            ln1_g + l * 512, ln1_b + l * 512, xb);
    // FFN1 -> hb (bf16, leaky)
    gemm_bt<<<dim3(16, 17, 1), 256, 0, stream>>>(
        xb, HIDDEN, W1t, HIDDEN, HIDDEN, 2,
        b1 + l * 2048, nullptr, nullptr, hb, nullptr, nullptr, nullptr, FFDIM);
    // FFN2: split-K(4) -> parts
    gemm_bt<<<dim3(4, 17, NSPLIT), 256, 0, stream>>>(
        hb, FFDIM, W2t, FFDIM, FFDIM, 1,
        nullptr, nullptr, nullptr, nullptr, nullptr, nullptr, parts, HIDDEN);
    ln_residual4<<<T_TOK, 256, 0, stream>>>(x, parts, b2 + l * 512,
                                            ln2_g + l * 512, ln2_b + l * 512, xb);
  }

  int n4 = T_TOK * HIDDEN / 4;
  copy_out<<<(n4 + 255) / 256, 256, 0, stream>>>((const float4*)x, (float4*)out, n4);
}

// Round 4
// 1003.654 us; speedup vs baseline: 20.5859x; 1.1851x over previous
//
#include <hip/hip_runtime.h>
#include <math.h>

#define T_TOK 2056
#define TP 2176      // 17*128  M-padded rows
#define TK 2112      // 33*64   KV-padded rows
#define HIDDEN 512
#define NHEAD 8
#define ADIM 64
#define FFDIM 2048
#define NLAYER 6
#define NORIG 520
#define NOBJ 8
#define NSPLIT 4     // flash KV splits and GEMM K-splits

typedef float f32x4 __attribute__((ext_vector_type(4)));
typedef __attribute__((__ext_vector_type__(8))) __bf16 bf16x8;

__device__ __forceinline__ unsigned short f2bf(float f) {
  unsigned int u = __float_as_uint(f);
  u += 0x7FFFu + ((u >> 16) & 1u);
  return (unsigned short)(u >> 16);
}
__device__ __forceinline__ float bf2f(unsigned short u) {
  return __uint_as_float(((unsigned int)u) << 16);
}

// ---------------- block reduction helpers (256 threads = 4 waves) ----------------

__device__ inline float blockReduceSum(float v, float* sb) {
#pragma unroll
  for (int off = 32; off > 0; off >>= 1) v += __shfl_down(v, off, 64);
  int wid = threadIdx.x >> 6;
  __syncthreads();
  if ((threadIdx.x & 63) == 0) sb[wid] = v;
  __syncthreads();
  return sb[0] + sb[1] + sb[2] + sb[3];
}

// ---------------- token embedding: project + LN + leaky_relu (fp32 + bf16 mirror) ----

__global__ __launch_bounds__(256) void embed_kernel(
    const float* __restrict__ obj, const float* __restrict__ st0,
    const float* __restrict__ Wpg, const float* __restrict__ bpg,
    const float* __restrict__ pg_g, const float* __restrict__ pg_b,
    const float* __restrict__ Wps, const float* __restrict__ bps,
    const float* __restrict__ ps_g, const float* __restrict__ ps_b,
    float* __restrict__ x, unsigned short* __restrict__ xb)
{
  __shared__ float sb[4];
  int t = blockIdx.x;
  int j0 = threadIdx.x, j1 = threadIdx.x + 256;
  float a0, a1;
  const float *g, *b;
  if (t < NOBJ) {
    a0 = bpg[j0]; a1 = bpg[j1];
    const float* in = obj + t * 100;
    for (int i = 0; i < 100; i++) {
      float w = in[i];
      a0 += w * Wpg[i * HIDDEN + j0];
      a1 += w * Wpg[i * HIDDEN + j1];
    }
    g = pg_g; b = pg_b;
  } else {
    int tt = t - NOBJ, s = tt >> 2, p = tt & 3;
    float c0 = st0[s * 10 + p * 2], c1 = st0[s * 10 + p * 2 + 1];
    a0 = bps[j0] + c0 * Wps[j0] + c1 * Wps[HIDDEN + j0];
    a1 = bps[j1] + c0 * Wps[j1] + c1 * Wps[HIDDEN + j1];
    g = ps_g; b = ps_b;
  }
  float s1 = blockReduceSum(a0 + a1, sb);
  float s2 = blockReduceSum(a0 * a0 + a1 * a1, sb);
  float m = s1 * (1.0f / HIDDEN);
  float var = s2 * (1.0f / HIDDEN) - m * m;
  float inv = rsqrtf(var + 1e-5f);
  float y0 = (a0 - m) * inv * g[j0] + b[j0];
  float y1 = (a1 - m) * inv * g[j1] + b[j1];
  y0 = y0 >= 0.f ? y0 : 0.01f * y0;
  y1 = y1 >= 0.f ? y1 : 0.01f * y1;
  x[t * HIDDEN + j0] = y0;
  x[t * HIDDEN + j1] = y1;
  xb[t * HIDDEN + j0] = f2bf(y0);
  xb[t * HIDDEN + j1] = f2bf(y1);
}

// zero xb pad rows (re-run every launch; ws is re-poisoned)
__global__ __launch_bounds__(256) void padzero(unsigned short* __restrict__ xb) {
  int i = blockIdx.x * 256 + threadIdx.x;
  if (i < (TP - T_TOK) * HIDDEN) xb[T_TOK * HIDDEN + i] = 0;
}

// ---------------- precompute rel-pos bias table: posb[h][520][520] (bf16) ----------

__global__ __launch_bounds__(256) void posbuild(
    const int* __restrict__ rpe_a, const int* __restrict__ rpe_d,
    const float* __restrict__ emb_a, const float* __restrict__ emb_d,
    const float* __restrict__ mask, unsigned short* __restrict__ posb)
{
  int i = blockIdx.x;
  for (int j = threadIdx.x; j < NORIG; j += 256) {
    int a = rpe_a[i * NORIG + j];
    int d = rpe_d[i * NORIG + j];
    float mk = mask[i * NORIG + j];
#pragma unroll
    for (int h = 0; h < NHEAD; h++) {
      float v = (emb_a[a * NHEAD + h] + emb_d[d * NHEAD + h]) * 0.125f + mk;
      posb[(h * NORIG + i) * NORIG + j] = f2bf(v);
    }
  }
}

// ---------------- weight transpose+convert: fp32 [K][N] -> bf16 [N][K] ----------------

__global__ __launch_bounds__(256) void wtrans(
    const float* __restrict__ Wq, const float* __restrict__ Wk, const float* __restrict__ Wv,
    const float* __restrict__ Wo, const float* __restrict__ W1, const float* __restrict__ W2,
    unsigned short* __restrict__ Wqkvt, unsigned short* __restrict__ Wot,
    unsigned short* __restrict__ W1t, unsigned short* __restrict__ W2t)
{
  __shared__ float t[64 * 65];
  int b = blockIdx.x;
  const float* src; unsigned short* dst; int N, K, tk, tn;
  if (b < 192) {
    int m = b >> 6, bb = b & 63;
    src = m == 0 ? Wq : m == 1 ? Wk : Wv;
    dst = Wqkvt + m * 512 * 512;
    K = 512; N = 512; tk = bb & 7; tn = bb >> 3;
  } else if (b < 256) {
    int bb = b - 192; src = Wo; dst = Wot; K = 512; N = 512; tk = bb & 7; tn = bb >> 3;
  } else if (b < 512) {
    int bb = b - 256; src = W1; dst = W1t; K = 512; N = 2048; tk = bb & 7; tn = bb >> 3;
  } else {
    int bb = b - 512; src = W2; dst = W2t; K = 2048; N = 512; tk = bb & 31; tn = bb >> 5;
  }
  int k0 = tk * 64, n0 = tn * 64;
  int tid = threadIdx.x;
  int r = tid >> 2, c0 = (tid & 3) * 16;
  const float* sp = src + (k0 + r) * N + n0 + c0;
#pragma unroll
  for (int q = 0; q < 4; q++) {
    float4 f = *(const float4*)(sp + q * 4);
    t[r * 65 + c0 + q * 4 + 0] = f.x;
    t[r * 65 + c0 + q * 4 + 1] = f.y;
    t[r * 65 + c0 + q * 4 + 2] = f.z;
    t[r * 65 + c0 + q * 4 + 3] = f.w;
  }
  __syncthreads();
  unsigned short vals[16];
#pragma unroll
  for (int j = 0; j < 16; j++) vals[j] = f2bf(t[(c0 + j) * 65 + r]);
  unsigned short* dp = dst + (n0 + r) * K + k0 + c0;
  *(int4*)dp = *(int4*)&vals[0];
  *(int4*)(dp + 8) = *(int4*)&vals[8];
}

// ---------------- MFMA GEMM: C[M=2176][N] = A[.][K] * Bt[N][K]^T, bf16 in / fp32 acc ----
// BM=64, BN=128, BK=32; 4 waves each 32x64 (2x4 of 16x16x32). LDS stride 40.
// Grids: QKV (12,34), FFN1 (16,34), Wo/FFN2 (4,34,4-splitK).
// mode 0: +bias(seg) -> scatter bf16 to qh/kh/vh [head][TP][64]
// mode 1: split-K partial -> fp32 df[z][TP][ldc] (NO bias)
// mode 2: +bias, leaky -> bf16 d0

__global__ __launch_bounds__(256) void gemm_bt(
    const unsigned short* __restrict__ A, int lda,
    const unsigned short* __restrict__ Bt, int ldb, int K, int mode,
    const float* __restrict__ b0, const float* __restrict__ b1, const float* __restrict__ b2,
    unsigned short* __restrict__ d0, unsigned short* __restrict__ d1, unsigned short* __restrict__ d2,
    float* __restrict__ df, int ldc)
{
  __shared__ unsigned short As[64 * 40];
  __shared__ unsigned short Bs[128 * 40];
  const int tid = threadIdx.x;
  const int lane = tid & 63, wave = tid >> 6;
  const int l15 = lane & 15, quad = lane >> 4;
  const int rowBase = blockIdx.y * 64, colBase = blockIdx.x * 128;
  const int mw = (wave & 1) * 32, nw = (wave >> 1) * 64;
  const int sr = tid >> 2, sc = (tid & 3) * 8;
  const int zz = blockIdx.z;
  const int kLen = K / gridDim.z;
  const int kb0 = zz * kLen;
  const unsigned short* Ag0 = A + (rowBase + sr) * lda + sc;
  const unsigned short* Bg0 = Bt + (colBase + sr) * ldb + sc;
  const unsigned short* Bg1 = Bg0 + 64 * ldb;
  f32x4 acc[2][4];
#pragma unroll
  for (int i = 0; i < 2; i++)
#pragma unroll
    for (int j = 0; j < 4; j++) acc[i][j] = (f32x4){0.f, 0.f, 0.f, 0.f};

  for (int kb = kb0; kb < kb0 + kLen; kb += 32) {
    int4 a0 = *(const int4*)(Ag0 + kb);
    int4 g0 = *(const int4*)(Bg0 + kb);
    int4 g1 = *(const int4*)(Bg1 + kb);
    __syncthreads();
    *(int4*)&As[sr * 40 + sc] = a0;
    *(int4*)&Bs[sr * 40 + sc] = g0;
    *(int4*)&Bs[(sr + 64) * 40 + sc] = g1;
    __syncthreads();
    bf16x8 af[2], bfr[4];
#pragma unroll
    for (int mt = 0; mt < 2; mt++)
      af[mt] = *(const bf16x8*)&As[(mw + mt * 16 + l15) * 40 + quad * 8];
#pragma unroll
    for (int nt = 0; nt < 4; nt++)
      bfr[nt] = *(const bf16x8*)&Bs[(nw + nt * 16 + l15) * 40 + quad * 8];
#pragma unroll
    for (int mt = 0; mt < 2; mt++)
#pragma unroll
      for (int nt = 0; nt < 4; nt++)
        acc[mt][nt] = __builtin_amdgcn_mfma_f32_16x16x32_bf16(af[mt], bfr[nt], acc[mt][nt], 0, 0, 0);
  }

  float* dfz = df + (size_t)zz * TP * ldc;
#pragma unroll
  for (int mt = 0; mt < 2; mt++) {
#pragma unroll
    for (int nt = 0; nt < 4; nt++) {
#pragma unroll
      for (int r = 0; r < 4; r++) {
        int row = rowBase + mw + mt * 16 + quad * 4 + r;
        int col = colBase + nw + nt * 16 + l15;
        float v = acc[mt][nt][r];
        if (mode == 0) {
          int seg = col >> 9, cc = col & 511;
          const float* bs = seg == 0 ? b0 : seg == 1 ? b1 : b2;
          unsigned short* dst = seg == 0 ? d0 : seg == 1 ? d1 : d2;
          int hd = cc >> 6, d = cc & 63;
          dst[(hd * TP + row) * 64 + d] = f2bf(v + bs[cc]);
        } else if (mode == 1) {
          dfz[row * ldc + col] = v;
        } else {
          float t = v + b0[col];
          t = t >= 0.f ? t : 0.01f * t;
          d0[row * ldc + col] = f2bf(t);
        }
      }
    }
  }
}

// ---------------- V transpose: vh [h][TP][64] -> vt [h][64][TK] ----------------

__global__ __launch_bounds__(256) void vt_trans(
    const unsigned short* __restrict__ vh, unsigned short* __restrict__ vt)
{
  __shared__ unsigned short t[64 * 72];
  int kt = blockIdx.x, h = blockIdx.y;
  int tid = threadIdx.x;
  int r0 = tid >> 3, cs = (tid & 7) * 8;
  const unsigned short* src = vh + (h * TP + kt * 64 + r0) * 64 + cs;
  *(int4*)&t[r0 * 72 + cs] = *(const int4*)src;
  *(int4*)&t[(r0 + 32) * 72 + cs] = *(const int4*)(src + 32 * 64);
  __syncthreads();
  int d = tid >> 2, c0 = (tid & 3) * 16;
  unsigned short vals[16];
#pragma unroll
  for (int j = 0; j < 16; j++) vals[j] = t[(c0 + j) * 72 + d];
  unsigned short* dst = vt + (h * 64 + d) * TK + kt * 64 + c0;
  *(int4*)dst = *(int4*)&vals[0];
  *(int4*)(dst + 8) = *(int4*)&vals[8];
}

// ---------------- split-KV flash attention, shift-free softmax ----------------
// Softmax is shift-invariant; scores here are O(1) so exp() directly (guard fmin 60).
// Row-sum l computed BY MFMA via a 5th V n-tile whose col0 is all-ones -> O[4] = l.
// No cross-lane ops in the k-loop at all. m == 0 is written for the merge.

__global__ __launch_bounds__(256) void flash_attn(
    const unsigned short* __restrict__ qh, const unsigned short* __restrict__ kh,
    const unsigned short* __restrict__ vt, const unsigned short* __restrict__ posb,
    float* __restrict__ Opart, float* __restrict__ ml)
{
  __shared__ unsigned short Ks[64 * 72];
  __shared__ unsigned short Vs[80 * 88];   // rows 0-63: V^T (d,k); rows 64-79: ones-col tile
  __shared__ unsigned short Ps[64 * 72];
  __shared__ float pt[24 * 24];
  const int tid = threadIdx.x;
  const int lane = tid & 63, wave = tid >> 6;
  const int l15 = lane & 15, quad = lane >> 4;
  const int qt = blockIdx.x, h = blockIdx.y, z = blockIdx.z;
  const int q0 = qt * 64;
  const int qrow = q0 + wave * 16 + l15;
  const unsigned short* qbp = qh + (h * TP + qrow) * 64;
  bf16x8 qf0 = *(const bf16x8*)(qbp + quad * 8);
  bf16x8 qf1 = *(const bf16x8*)(qbp + 32 + quad * 8);
  f32x4 O[5];
#pragma unroll
  for (int nt = 0; nt < 5; nt++) O[nt] = (f32x4){0.f, 0.f, 0.f, 0.f};
  // ones-tile: B[n=64][k]=1, B[n=65..79][k]=0  (written once; staging never touches it)
  for (int idx = tid; idx < 16 * 88; idx += 256) {
    int rr = idx / 88, cc = idx - rr * 88;
    Vs[(64 + rr) * 88 + cc] = (rr == 0) ? 0x3F80 : 0;
  }
  const int oq0 = q0 < 8 ? q0 : 8 + ((q0 - 8) >> 2);
  const int qe = min(q0 + 63, T_TOK - 1);
  const int nq = (qe < 8 ? qe : 8 + ((qe - 8) >> 2)) - oq0 + 1;
  int myq[4];
#pragma unroll
  for (int r = 0; r < 4; r++) {
    int qr = q0 + wave * 16 + quad * 4 + r;
    myq[r] = (qr < 8 ? qr : 8 + ((qr - 8) >> 2)) - oq0;
  }
  const int sr = tid >> 3, sc = (tid & 7) * 8;
  const unsigned short* kgb = kh + (h * TP + sr) * 64 + sc;
  const unsigned short* vgb = vt + (h * 64 + sr) * TK + sc;
  const int ptrow = tid >> 3, ptc0 = (tid & 7) * 3;

  const int kt0 = z * 9, kt1 = min(33, kt0 + 9);
  for (int kt = kt0; kt < kt1; kt++) {
    const int kb = kt * 64;
    int4 kv0 = *(const int4*)(kgb + kb * 64);
    int4 kv1 = *(const int4*)(kgb + (kb + 32) * 64);
    int4 vv0 = *(const int4*)(vgb + kb);
    int4 vv1 = *(const int4*)(vgb + 32 * TK + kb);
    const int ok0 = kb < 8 ? kb : 8 + ((kb - 8) >> 2);
    const int ke = min(kb + 63, T_TOK - 1);
    const int nk = (ke < 8 ? ke : 8 + ((ke - 8) >> 2)) - ok0 + 1;
    __syncthreads();  // prev iter's LDS reads complete
    *(int4*)&Ks[sr * 72 + sc] = kv0;
    *(int4*)&Ks[(sr + 32) * 72 + sc] = kv1;
    *(int4*)&Vs[sr * 88 + sc] = vv0;
    *(int4*)&Vs[(sr + 32) * 88 + sc] = vv1;
    if (ptrow < 24) {
      const unsigned short* prow = posb + (h * NORIG + oq0 + ptrow) * NORIG + ok0;
      bool rok = ptrow < nq;
#pragma unroll
      for (int c = 0; c < 3; c++) {
        int col = ptc0 + c;
        pt[ptrow * 24 + col] = (rok && col < nk) ? bf2f(prow[col]) : 0.f;
      }
    }
    __syncthreads();
    // S = Q K^T
    f32x4 S[4];
#pragma unroll
    for (int nt = 0; nt < 4; nt++) S[nt] = (f32x4){0.f, 0.f, 0.f, 0.f};
#pragma unroll
    for (int nt = 0; nt < 4; nt++) {
      bf16x8 kf0 = *(const bf16x8*)&Ks[(nt * 16 + l15) * 72 + quad * 8];
      bf16x8 kf1 = *(const bf16x8*)&Ks[(nt * 16 + l15) * 72 + 32 + quad * 8];
      S[nt] = __builtin_amdgcn_mfma_f32_16x16x32_bf16(qf0, kf0, S[nt], 0, 0, 0);
      S[nt] = __builtin_amdgcn_mfma_f32_16x16x32_bf16(qf1, kf1, S[nt], 0, 0, 0);
    }
    int okp[4], colv[4];
#pragma unroll
    for (int nt = 0; nt < 4; nt++) {
      int c = kb + nt * 16 + l15;
      colv[nt] = c;
      okp[nt] = (c < 8 ? c : 8 + ((c - 8) >> 2)) - ok0;
    }
#pragma unroll
    for (int r = 0; r < 4; r++) {
      int pr = wave * 16 + quad * 4 + r;
#pragma unroll
      for (int nt = 0; nt < 4; nt++) {
        float a = (colv[nt] < T_TOK)
                    ? fminf(S[nt][r] * 0.125f + pt[myq[r] * 24 + okp[nt]], 60.f)
                    : -1e30f;
        Ps[pr * 72 + nt * 16 + l15] = f2bf(__expf(a));
      }
    }
    __syncthreads();  // Ps visible
    // O += P V  (5th n-tile accumulates l in O[4], lane l15==0)
    bf16x8 pa0 = *(const bf16x8*)&Ps[(wave * 16 + l15) * 72 + quad * 8];
    bf16x8 pa1 = *(const bf16x8*)&Ps[(wave * 16 + l15) * 72 + 32 + quad * 8];
#pragma unroll
    for (int nt = 0; nt < 5; nt++) {
      bf16x8 vb0 = *(const bf16x8*)&Vs[(nt * 16 + l15) * 88 + quad * 8];
      bf16x8 vb1 = *(const bf16x8*)&Vs[(nt * 16 + l15) * 88 + 32 + quad * 8];
      O[nt] = __builtin_amdgcn_mfma_f32_16x16x32_bf16(pa0, vb0, O[nt], 0, 0, 0);
      O[nt] = __builtin_amdgcn_mfma_f32_16x16x32_bf16(pa1, vb1, O[nt], 0, 0, 0);
    }
  }
#pragma unroll
  for (int r = 0; r < 4; r++) {
    float lsum = __shfl(O[4][r], lane & 48, 64);  // broadcast l from l15==0 of own quad
    int orow = q0 + wave * 16 + quad * 4 + r;
    size_t base = ((size_t)(z * NHEAD + h) * TK + orow);
    if (l15 == 0) {
      ml[base * 2] = 0.f;
      ml[base * 2 + 1] = lsum;
    }
#pragma unroll
    for (int nt = 0; nt < 4; nt++)
      Opart[base * 64 + nt * 16 + l15] = O[nt][r];
  }
}

// ---------------- merge flash splits -> ob (bf16 [T][512]) ----------------

__global__ __launch_bounds__(256) void flash_merge(
    const float* __restrict__ Opart, const float* __restrict__ ml,
    unsigned short* __restrict__ ob)
{
  int idx = blockIdx.x * 256 + threadIdx.x;
  if (idx >= T_TOK * HIDDEN) return;
  int row = idx >> 9, c = idx & 511;
  int h = c >> 6, d = c & 63;
  float M = -1e30f;
  float mv[NSPLIT], lv[NSPLIT];
#pragma unroll
  for (int s = 0; s < NSPLIT; s++) {
    size_t base = ((size_t)(s * NHEAD + h) * TK + row);
    mv[s] = ml[base * 2];
    lv[s] = ml[base * 2 + 1];
    M = fmaxf(M, mv[s]);
  }
  float num = 0.f, den = 0.f;
#pragma unroll
  for (int s = 0; s < NSPLIT; s++) {
    float w = __expf(mv[s] - M);
    den += w * lv[s];
    num += w * Opart[((size_t)(s * NHEAD + h) * TK + row) * 64 + d];
  }
  ob[idx] = f2bf(num / den);
}

// ---------------- residual + bias + 4-way split-K sum + LN, fp32 + bf16 mirror -------

__global__ __launch_bounds__(256) void ln_residual4(
    float* __restrict__ x, const float* __restrict__ parts,
    const float* __restrict__ bias,
    const float* __restrict__ g, const float* __restrict__ b,
    unsigned short* __restrict__ xb)
{
  __shared__ float sb[4];
  int row = blockIdx.x;
  int j0 = threadIdx.x, j1 = threadIdx.x + 256;
  int base = row * HIDDEN;
  const size_t ss = (size_t)TP * HIDDEN;
  float v0 = x[base + j0] + bias[j0] + parts[base + j0] + parts[ss + base + j0]
           + parts[2 * ss + base + j0] + parts[3 * ss + base + j0];
  float v1 = x[base + j1] + bias[j1] + parts[base + j1] + parts[ss + base + j1]
           + parts[2 * ss + base + j1] + parts[3 * ss + base + j1];
  float s1 = blockReduceSum(v0 + v1, sb);
  float s2 = blockReduceSum(v0 * v0 + v1 * v1, sb);
  float m = s1 * (1.0f / HIDDEN);
  float var = s2 * (1.0f / HIDDEN) - m * m;
  float inv = rsqrtf(var + 1e-5f);
  float y0 = (v0 - m) * inv * g[j0] + b[j0];
  float y1 = (v1 - m) * inv * g[j1] + b[j1];
  x[base + j0] = y0;
  x[base + j1] = y1;
  xb[base + j0] = f2bf(y0);
  xb[base + j1] = f2bf(y1);
}

__global__ __launch_bounds__(256) void copy_out(
    const float4* __restrict__ src, float4* __restrict__ dst, int n4)
{
  int i = blockIdx.x * 256 + threadIdx.x;
  if (i < n4) dst[i] = src[i];
}

// ---------------- driver ----------------

extern "C" void kernel_launch(void* const* d_in, const int* in_sizes, int n_in,
                              void* d_out, int out_size, void* d_ws, size_t ws_size,
                              hipStream_t stream) {
  const float* obj   = (const float*)d_in[0];
  const float* st0   = (const float*)d_in[2];
  const int*   rpe_a = (const int*)d_in[3];
  const int*   rpe_d = (const int*)d_in[4];
  const float* mask  = (const float*)d_in[5];
  const float* Wpg = (const float*)d_in[6];  const float* bpg = (const float*)d_in[7];
  const float* pg_g = (const float*)d_in[8]; const float* pg_b = (const float*)d_in[9];
  const float* Wps = (const float*)d_in[10]; const float* bps = (const float*)d_in[11];
  const float* ps_g = (const float*)d_in[12];const float* ps_b = (const float*)d_in[13];
  const float* emb_a = (const float*)d_in[14];
  const float* emb_d = (const float*)d_in[15];
  const float* Wq = (const float*)d_in[16]; const float* bq = (const float*)d_in[17];
  const float* Wk = (const float*)d_in[18]; const float* bk = (const float*)d_in[19];
  const float* Wv = (const float*)d_in[20]; const float* bv = (const float*)d_in[21];
  const float* Wo = (const float*)d_in[22]; const float* bo = (const float*)d_in[23];
  const float* W1 = (const float*)d_in[24]; const float* b1 = (const float*)d_in[25];
  const float* W2 = (const float*)d_in[26]; const float* b2 = (const float*)d_in[27];
  const float* ln1_g = (const float*)d_in[28]; const float* ln1_b = (const float*)d_in[29];
  const float* ln2_g = (const float*)d_in[30]; const float* ln2_b = (const float*)d_in[31];

  // ---- workspace layout (phase-disjoint unions; total ~46 MB) ----
  char* p = (char*)d_ws;
  auto alloc = [&](size_t bytes) { char* q = p; p += (bytes + 255) & ~(size_t)255; return q; };
  float*          x      = (float*)alloc((size_t)T_TOK * HIDDEN * 4);
  unsigned short* xb     = (unsigned short*)alloc((size_t)TP * HIDDEN * 2);
  // union1: {qhb,khb,vhb,vtb} (attention phase) | hb (FFN phase)
  char*           u1     = (char*)alloc((size_t)TP * FFDIM * 2);
  unsigned short* qhb    = (unsigned short*)u1;
  unsigned short* khb    = qhb + (size_t)NHEAD * TP * ADIM;
  unsigned short* vhb    = khb + (size_t)NHEAD * TP * ADIM;
  unsigned short* vtb    = vhb + (size_t)NHEAD * TP * ADIM;
  unsigned short* hb     = (unsigned short*)u1;
  unsigned short* ob     = (unsigned short*)alloc((size_t)TP * HIDDEN * 2);
  // union2: {Opart+ml} (flash) | parts (split-K GEMM)
  char*           u2     = (char*)alloc((size_t)NSPLIT * NHEAD * TK * ADIM * 4 + (size_t)NSPLIT * NHEAD * TK * 2 * 4);
  float*          Opart  = (float*)u2;
  float*          mlb    = Opart + (size_t)NSPLIT * NHEAD * TK * ADIM;
  float*          parts  = (float*)u2;
  unsigned short* posb   = (unsigned short*)alloc((size_t)NHEAD * NORIG * NORIG * 2);
  unsigned short* Wqkvt  = (unsigned short*)alloc((size_t)1536 * 512 * 2);
  unsigned short* Wot    = (unsigned short*)alloc((size_t)512 * 512 * 2);
  unsigned short* W1t    = (unsigned short*)alloc((size_t)2048 * 512 * 2);
  unsigned short* W2t    = (unsigned short*)alloc((size_t)512 * 2048 * 2);
  if ((size_t)(p - (char*)d_ws) > ws_size) return;

  float* out = (float*)d_out;

  embed_kernel<<<T_TOK, 256, 0, stream>>>(obj, st0, Wpg, bpg, pg_g, pg_b,
                                          Wps, bps, ps_g, ps_b, x, xb);
  padzero<<<((TP - T_TOK) * HIDDEN + 255) / 256, 256, 0, stream>>>(xb);
  posbuild<<<NORIG, 256, 0, stream>>>(rpe_a, rpe_d, emb_a, emb_d, mask, posb);

  for (int l = 0; l < NLAYER; l++) {
    wtrans<<<768, 256, 0, stream>>>(
        Wq + l * 512 * 512, Wk + l * 512 * 512, Wv + l * 512 * 512,
        Wo + l * 512 * 512, W1 + l * 512 * 2048, W2 + l * 2048 * 512,
        Wqkvt, Wot, W1t, W2t);
    // QKV (N=1536 packed)
    gemm_bt<<<dim3(12, 34, 1), 256, 0, stream>>>(
        xb, HIDDEN, Wqkvt, HIDDEN, HIDDEN, 0,
        bq + l * 512, bk + l * 512, bv + l * 512, qhb, khb, vhb, nullptr, 0);
    vt_trans<<<dim3(33, 8), 256, 0, stream>>>(vhb, vtb);
    flash_attn<<<dim3(33, 8, NSPLIT), 256, 0, stream>>>(
        qhb, khb, vtb, posb, Opart, mlb);
    flash_merge<<<(T_TOK * HIDDEN + 255) / 256, 256, 0, stream>>>(Opart, mlb, ob);
    // O projection: split-K(4) -> parts, reduce fused into LN
    gemm_bt<<<dim3(4, 34, NSPLIT), 256, 0, stream>>>(
        ob, HIDDEN, Wot, HIDDEN, HIDDEN, 1,
        nullptr, nullptr, nullptr, nullptr, nullptr, nullptr, parts, HIDDEN);
    ln_residual4<<<T_TOK, 256, 0, stream>>>(x, parts, bo + l * 512,
                                            ln1_g + l * 512, ln1_b + l * 512, xb);
    // FFN1 -> hb (bf16, leaky)
    gemm_bt<<<dim3(16, 34, 1), 256, 0, stream>>>(
        xb, HIDDEN, W1t, HIDDEN, HIDDEN, 2,
        b1 + l * 2048, nullptr, nullptr, hb, nullptr, nullptr, nullptr, FFDIM);
    // FFN2: split-K(4) -> parts
    gemm_bt<<<dim3(4, 34, NSPLIT), 256, 0, stream>>>(
        hb, FFDIM, W2t, FFDIM, FFDIM, 1,
        nullptr, nullptr, nullptr, nullptr, nullptr, nullptr, parts, HIDDEN);
    ln_residual4<<<T_TOK, 256, 0, stream>>>(x, parts, b2 + l * 512,
                                            ln2_g + l * 512, ln2_b + l * 512, xb);
  }

  int n4 = T_TOK * HIDDEN / 4;
  copy_out<<<(n4 + 255) / 256, 256, 0, stream>>>((const float4*)x, (float4*)out, n4);
}

// Round 5
// 960.797 us; speedup vs baseline: 21.5042x; 1.0446x over previous
//
#include <hip/hip_runtime.h>
#include <math.h>

#define T_TOK 2056
#define TP 2176      // 17*128  M-padded rows
#define TK 2112      // 33*64   KV-padded rows
#define HIDDEN 512
#define NHEAD 8
#define ADIM 64
#define FFDIM 2048
#define NLAYER 6
#define NORIG 520
#define NOBJ 8
#define NSPLIT 4     // GEMM K-splits
#define FSPLIT 8     // flash KV splits

typedef float f32x4 __attribute__((ext_vector_type(4)));
typedef __attribute__((__ext_vector_type__(8))) __bf16 bf16x8;

#if __has_builtin(__builtin_amdgcn_exp2f)
#define EXP2(x) __builtin_amdgcn_exp2f(x)
#else
#define EXP2(x) exp2f(x)
#endif

__device__ __forceinline__ unsigned short f2bf(float f) {
  unsigned int u = __float_as_uint(f);
  u += 0x7FFFu + ((u >> 16) & 1u);
  return (unsigned short)(u >> 16);
}
__device__ __forceinline__ float bf2f(unsigned short u) {
  return __uint_as_float(((unsigned int)u) << 16);
}

// ---------------- block reduction helpers (256 threads = 4 waves) ----------------

__device__ inline float blockReduceSum(float v, float* sb) {
#pragma unroll
  for (int off = 32; off > 0; off >>= 1) v += __shfl_down(v, off, 64);
  int wid = threadIdx.x >> 6;
  __syncthreads();
  if ((threadIdx.x & 63) == 0) sb[wid] = v;
  __syncthreads();
  return sb[0] + sb[1] + sb[2] + sb[3];
}

// ---------------- token embedding: project + LN + leaky_relu (fp32 + bf16 mirror) ----

__global__ __launch_bounds__(256) void embed_kernel(
    const float* __restrict__ obj, const float* __restrict__ st0,
    const float* __restrict__ Wpg, const float* __restrict__ bpg,
    const float* __restrict__ pg_g, const float* __restrict__ pg_b,
    const float* __restrict__ Wps, const float* __restrict__ bps,
    const float* __restrict__ ps_g, const float* __restrict__ ps_b,
    float* __restrict__ x, unsigned short* __restrict__ xb)
{
  __shared__ float sb[4];
  int t = blockIdx.x;
  int j0 = threadIdx.x, j1 = threadIdx.x + 256;
  float a0, a1;
  const float *g, *b;
  if (t < NOBJ) {
    a0 = bpg[j0]; a1 = bpg[j1];
    const float* in = obj + t * 100;
    for (int i = 0; i < 100; i++) {
      float w = in[i];
      a0 += w * Wpg[i * HIDDEN + j0];
      a1 += w * Wpg[i * HIDDEN + j1];
    }
    g = pg_g; b = pg_b;
  } else {
    int tt = t - NOBJ, s = tt >> 2, p = tt & 3;
    float c0 = st0[s * 10 + p * 2], c1 = st0[s * 10 + p * 2 + 1];
    a0 = bps[j0] + c0 * Wps[j0] + c1 * Wps[HIDDEN + j0];
    a1 = bps[j1] + c0 * Wps[j1] + c1 * Wps[HIDDEN + j1];
    g = ps_g; b = ps_b;
  }
  float s1 = blockReduceSum(a0 + a1, sb);
  float s2 = blockReduceSum(a0 * a0 + a1 * a1, sb);
  float m = s1 * (1.0f / HIDDEN);
  float var = s2 * (1.0f / HIDDEN) - m * m;
  float inv = rsqrtf(var + 1e-5f);
  float y0 = (a0 - m) * inv * g[j0] + b[j0];
  float y1 = (a1 - m) * inv * g[j1] + b[j1];
  y0 = y0 >= 0.f ? y0 : 0.01f * y0;
  y1 = y1 >= 0.f ? y1 : 0.01f * y1;
  x[t * HIDDEN + j0] = y0;
  x[t * HIDDEN + j1] = y1;
  xb[t * HIDDEN + j0] = f2bf(y0);
  xb[t * HIDDEN + j1] = f2bf(y1);
}

// zero xb pad rows (re-run every launch; ws is re-poisoned)
__global__ __launch_bounds__(256) void padzero(unsigned short* __restrict__ xb) {
  int i = blockIdx.x * 256 + threadIdx.x;
  if (i < (TP - T_TOK) * HIDDEN) xb[T_TOK * HIDDEN + i] = 0;
}

// ---------------- precompute rel-pos bias table: posb[h][520][520] (bf16) ----------
// posb = ((emb_a[rpe_a]+emb_d[rpe_d]) * 0.125 + mask) * log2(e)   (layer-invariant)

__global__ __launch_bounds__(256) void posbuild(
    const int* __restrict__ rpe_a, const int* __restrict__ rpe_d,
    const float* __restrict__ emb_a, const float* __restrict__ emb_d,
    const float* __restrict__ mask, unsigned short* __restrict__ posb)
{
  int i = blockIdx.x;
  for (int j = threadIdx.x; j < NORIG; j += 256) {
    int a = rpe_a[i * NORIG + j];
    int d = rpe_d[i * NORIG + j];
    float mk = mask[i * NORIG + j];
#pragma unroll
    for (int h = 0; h < NHEAD; h++) {
      float v = ((emb_a[a * NHEAD + h] + emb_d[d * NHEAD + h]) * 0.125f + mk) * 1.44269504f;
      posb[(h * NORIG + i) * NORIG + j] = f2bf(v);
    }
  }
}

// ---------------- weight transpose+convert: fp32 [K][N] -> bf16 [N][K] ----------------

__global__ __launch_bounds__(256) void wtrans(
    const float* __restrict__ Wq, const float* __restrict__ Wk, const float* __restrict__ Wv,
    const float* __restrict__ Wo, const float* __restrict__ W1, const float* __restrict__ W2,
    unsigned short* __restrict__ Wqkvt, unsigned short* __restrict__ Wot,
    unsigned short* __restrict__ W1t, unsigned short* __restrict__ W2t)
{
  __shared__ float t[64 * 65];
  int b = blockIdx.x;
  const float* src; unsigned short* dst; int N, K, tk, tn;
  if (b < 192) {
    int m = b >> 6, bb = b & 63;
    src = m == 0 ? Wq : m == 1 ? Wk : Wv;
    dst = Wqkvt + m * 512 * 512;
    K = 512; N = 512; tk = bb & 7; tn = bb >> 3;
  } else if (b < 256) {
    int bb = b - 192; src = Wo; dst = Wot; K = 512; N = 512; tk = bb & 7; tn = bb >> 3;
  } else if (b < 512) {
    int bb = b - 256; src = W1; dst = W1t; K = 512; N = 2048; tk = bb & 7; tn = bb >> 3;
  } else {
    int bb = b - 512; src = W2; dst = W2t; K = 2048; N = 512; tk = bb & 31; tn = bb >> 5;
  }
  int k0 = tk * 64, n0 = tn * 64;
  int tid = threadIdx.x;
  int r = tid >> 2, c0 = (tid & 3) * 16;
  const float* sp = src + (k0 + r) * N + n0 + c0;
#pragma unroll
  for (int q = 0; q < 4; q++) {
    float4 f = *(const float4*)(sp + q * 4);
    t[r * 65 + c0 + q * 4 + 0] = f.x;
    t[r * 65 + c0 + q * 4 + 1] = f.y;
    t[r * 65 + c0 + q * 4 + 2] = f.z;
    t[r * 65 + c0 + q * 4 + 3] = f.w;
  }
  __syncthreads();
  unsigned short vals[16];
#pragma unroll
  for (int j = 0; j < 16; j++) vals[j] = f2bf(t[(c0 + j) * 65 + r]);
  unsigned short* dp = dst + (n0 + r) * K + k0 + c0;
  *(int4*)dp = *(int4*)&vals[0];
  *(int4*)(dp + 8) = *(int4*)&vals[8];
}

// ---------------- MFMA GEMM: C[M=2176][N] = A[.][K] * Bt[N][K]^T, bf16 in / fp32 acc ----
// BM=64, BN=128, BK=32; 4 waves each 32x64. Double-buffered LDS, ONE barrier per
// k-iter, global loads for iter i+1 issued before compute of iter i.
// mode 0: +bias(seg) -> scatter bf16 to qh/kh/vh [head][TP][64]; Q scaled 0.125*log2e
// mode 1: split-K partial -> fp32 df[z][TP][ldc] (NO bias)
// mode 2: +bias, leaky -> bf16 d0

__global__ __launch_bounds__(256) void gemm_bt(
    const unsigned short* __restrict__ A, int lda,
    const unsigned short* __restrict__ Bt, int ldb, int K, int mode,
    const float* __restrict__ b0, const float* __restrict__ b1, const float* __restrict__ b2,
    unsigned short* __restrict__ d0, unsigned short* __restrict__ d1, unsigned short* __restrict__ d2,
    float* __restrict__ df, int ldc)
{
  __shared__ unsigned short As[2][64 * 40];
  __shared__ unsigned short Bs[2][128 * 40];
  const int tid = threadIdx.x;
  const int lane = tid & 63, wave = tid >> 6;
  const int l15 = lane & 15, quad = lane >> 4;
  const int rowBase = blockIdx.y * 64, colBase = blockIdx.x * 128;
  const int mw = (wave & 1) * 32, nw = (wave >> 1) * 64;
  const int sr = tid >> 2, sc = (tid & 3) * 8;
  const int zz = blockIdx.z;
  const int kLen = K / gridDim.z;
  const int kb0 = zz * kLen;
  const int nIter = kLen >> 5;
  const unsigned short* Ag0 = A + (rowBase + sr) * lda + sc;
  const unsigned short* Bg0 = Bt + (colBase + sr) * ldb + sc;
  const unsigned short* Bg1 = Bg0 + 64 * ldb;
  f32x4 acc[2][4];
#pragma unroll
  for (int i = 0; i < 2; i++)
#pragma unroll
    for (int j = 0; j < 4; j++) acc[i][j] = (f32x4){0.f, 0.f, 0.f, 0.f};

  int4 a0 = *(const int4*)(Ag0 + kb0);
  int4 g0 = *(const int4*)(Bg0 + kb0);
  int4 g1 = *(const int4*)(Bg1 + kb0);
  *(int4*)&As[0][sr * 40 + sc] = a0;
  *(int4*)&Bs[0][sr * 40 + sc] = g0;
  *(int4*)&Bs[0][(sr + 64) * 40 + sc] = g1;

  for (int it = 0; it < nIter; ++it) {
    __syncthreads();                       // buf[it&1] complete; buf[(it+1)&1] free
    const int cur = it & 1, nxt = cur ^ 1;
    const bool more = (it + 1) < nIter;
    if (more) {
      int kb = kb0 + (it + 1) * 32;
      a0 = *(const int4*)(Ag0 + kb);
      g0 = *(const int4*)(Bg0 + kb);
      g1 = *(const int4*)(Bg1 + kb);
    }
    bf16x8 af[2], bfr[4];
#pragma unroll
    for (int mt = 0; mt < 2; mt++)
      af[mt] = *(const bf16x8*)&As[cur][(mw + mt * 16 + l15) * 40 + quad * 8];
#pragma unroll
    for (int nt = 0; nt < 4; nt++)
      bfr[nt] = *(const bf16x8*)&Bs[cur][(nw + nt * 16 + l15) * 40 + quad * 8];
#pragma unroll
    for (int mt = 0; mt < 2; mt++)
#pragma unroll
      for (int nt = 0; nt < 4; nt++)
        acc[mt][nt] = __builtin_amdgcn_mfma_f32_16x16x32_bf16(af[mt], bfr[nt], acc[mt][nt], 0, 0, 0);
    if (more) {
      *(int4*)&As[nxt][sr * 40 + sc] = a0;
      *(int4*)&Bs[nxt][sr * 40 + sc] = g0;
      *(int4*)&Bs[nxt][(sr + 64) * 40 + sc] = g1;
    }
  }

  float* dfz = df + (size_t)zz * TP * ldc;
#pragma unroll
  for (int mt = 0; mt < 2; mt++) {
#pragma unroll
    for (int nt = 0; nt < 4; nt++) {
#pragma unroll
      for (int r = 0; r < 4; r++) {
        int row = rowBase + mw + mt * 16 + quad * 4 + r;
        int col = colBase + nw + nt * 16 + l15;
        float v = acc[mt][nt][r];
        if (mode == 0) {
          int seg = col >> 9, cc = col & 511;
          const float* bs = seg == 0 ? b0 : seg == 1 ? b1 : b2;
          unsigned short* dst = seg == 0 ? d0 : seg == 1 ? d1 : d2;
          int hd = cc >> 6, d = cc & 63;
          float t = v + bs[cc];
          if (seg == 0) t *= 0.180336880111f;  // 0.125 * log2(e) folded into Q
          dst[(hd * TP + row) * 64 + d] = f2bf(t);
        } else if (mode == 1) {
          dfz[row * ldc + col] = v;
        } else {
          float t = v + b0[col];
          t = t >= 0.f ? t : 0.01f * t;
          d0[row * ldc + col] = f2bf(t);
        }
      }
    }
  }
}

// ---------------- V transpose: vh [h][TP][64] -> vt [h][64][TK] ----------------

__global__ __launch_bounds__(256) void vt_trans(
    const unsigned short* __restrict__ vh, unsigned short* __restrict__ vt)
{
  __shared__ unsigned short t[64 * 72];
  int kt = blockIdx.x, h = blockIdx.y;
  int tid = threadIdx.x;
  int r0 = tid >> 3, cs = (tid & 7) * 8;
  const unsigned short* src = vh + (h * TP + kt * 64 + r0) * 64 + cs;
  *(int4*)&t[r0 * 72 + cs] = *(const int4*)src;
  *(int4*)&t[(r0 + 32) * 72 + cs] = *(const int4*)(src + 32 * 64);
  __syncthreads();
  int d = tid >> 2, c0 = (tid & 3) * 16;
  unsigned short vals[16];
#pragma unroll
  for (int j = 0; j < 16; j++) vals[j] = t[(c0 + j) * 72 + d];
  unsigned short* dst = vt + (h * 64 + d) * TK + kt * 64 + c0;
  *(int4*)dst = *(int4*)&vals[0];
  *(int4*)(dst + 8) = *(int4*)&vals[8];
}

// ---------------- split-KV flash attention, shift-free exp2 softmax, pipelined -------
// grid (33 q-tiles, 8 heads, FSPLIT); split z handles tiles kt = z, z+FSPLIT, ...
// Next tile's K/V/pos prefetched into regs during current tile's compute.
// Ps write->read is wave-local: no barrier needed between epilogue and PV.
// Row-sum l via ones-column 5th V n-tile (O[4]). Opart stored bf16; m == 0 implied.

__global__ __launch_bounds__(256) void flash_attn(
    const unsigned short* __restrict__ qh, const unsigned short* __restrict__ kh,
    const unsigned short* __restrict__ vt, const unsigned short* __restrict__ posb,
    unsigned short* __restrict__ Opart, float* __restrict__ lbuf)
{
  __shared__ unsigned short Ks[64 * 72];
  __shared__ unsigned short Vs[80 * 88];   // rows 0-63: V^T; rows 64-79: ones-col tile
  __shared__ unsigned short Ps[64 * 72];
  __shared__ float pt[24 * 24];
  const int tid = threadIdx.x;
  const int lane = tid & 63, wave = tid >> 6;
  const int l15 = lane & 15, quad = lane >> 4;
  const int qt = blockIdx.x, h = blockIdx.y, z = blockIdx.z;
  const int q0 = qt * 64;
  const int qrow = q0 + wave * 16 + l15;
  const unsigned short* qbp = qh + (h * TP + qrow) * 64;
  bf16x8 qf0 = *(const bf16x8*)(qbp + quad * 8);
  bf16x8 qf1 = *(const bf16x8*)(qbp + 32 + quad * 8);
  f32x4 O[5];
#pragma unroll
  for (int nt = 0; nt < 5; nt++) O[nt] = (f32x4){0.f, 0.f, 0.f, 0.f};
  for (int idx = tid; idx < 16 * 88; idx += 256) {
    int rr = idx / 88, cc = idx - rr * 88;
    Vs[(64 + rr) * 88 + cc] = (rr == 0) ? 0x3F80 : 0;
  }
  const int oq0 = q0 < 8 ? q0 : 8 + ((q0 - 8) >> 2);
  const int qe = min(q0 + 63, T_TOK - 1);
  const int nq = (qe < 8 ? qe : 8 + ((qe - 8) >> 2)) - oq0 + 1;
  int myq[4];
#pragma unroll
  for (int r = 0; r < 4; r++) {
    int qr = q0 + wave * 16 + quad * 4 + r;
    myq[r] = (qr < 8 ? qr : 8 + ((qr - 8) >> 2)) - oq0;
  }
  const int sr = tid >> 3, sc = (tid & 7) * 8;
  const unsigned short* kgb = kh + (h * TP + sr) * 64 + sc;
  const unsigned short* vgb = vt + (h * 64 + sr) * TK + sc;
  const int ptrow = tid >> 3, ptc0 = (tid & 7) * 3;
  const bool prok = (ptrow < 24) && (ptrow < nq);

  const int nT = (33 - z + FSPLIT - 1) / FSPLIT;
  int kb = z * 64;
  // prefetch tile 0
  int4 kv0 = *(const int4*)(kgb + kb * 64);
  int4 kv1 = *(const int4*)(kgb + (kb + 32) * 64);
  int4 vv0 = *(const int4*)(vgb + kb);
  int4 vv1 = *(const int4*)(vgb + 32 * TK + kb);
  float ppf0, ppf1, ppf2;
  {
    int ok0n = kb < 8 ? kb : 8 + ((kb - 8) >> 2);
    int ken = min(kb + 63, T_TOK - 1);
    int nkn = (ken < 8 ? ken : 8 + ((ken - 8) >> 2)) - ok0n + 1;
    const unsigned short* prow = posb + (h * NORIG + oq0 + ptrow) * NORIG + ok0n;
    ppf0 = (prok && ptc0 + 0 < nkn) ? bf2f(prow[ptc0 + 0]) : 0.f;
    ppf1 = (prok && ptc0 + 1 < nkn) ? bf2f(prow[ptc0 + 1]) : 0.f;
    ppf2 = (prok && ptc0 + 2 < nkn) ? bf2f(prow[ptc0 + 2]) : 0.f;
  }

  for (int i = 0; i < nT; ++i) {
    const int kbCur = kb;
    const int ok0c = kbCur < 8 ? kbCur : 8 + ((kbCur - 8) >> 2);
    __syncthreads();                       // prev tile's LDS reads complete
    *(int4*)&Ks[sr * 72 + sc] = kv0;
    *(int4*)&Ks[(sr + 32) * 72 + sc] = kv1;
    *(int4*)&Vs[sr * 88 + sc] = vv0;
    *(int4*)&Vs[(sr + 32) * 88 + sc] = vv1;
    if (ptrow < 24) {
      pt[ptrow * 24 + ptc0 + 0] = ppf0;
      pt[ptrow * 24 + ptc0 + 1] = ppf1;
      pt[ptrow * 24 + ptc0 + 2] = ppf2;
    }
    __syncthreads();
    kb += FSPLIT * 64;
    if (i + 1 < nT) {                      // prefetch next tile during compute
      kv0 = *(const int4*)(kgb + kb * 64);
      kv1 = *(const int4*)(kgb + (kb + 32) * 64);
      vv0 = *(const int4*)(vgb + kb);
      vv1 = *(const int4*)(vgb + 32 * TK + kb);
      int ok0n = kb < 8 ? kb : 8 + ((kb - 8) >> 2);
      int ken = min(kb + 63, T_TOK - 1);
      int nkn = (ken < 8 ? ken : 8 + ((ken - 8) >> 2)) - ok0n + 1;
      const unsigned short* prow = posb + (h * NORIG + oq0 + ptrow) * NORIG + ok0n;
      ppf0 = (prok && ptc0 + 0 < nkn) ? bf2f(prow[ptc0 + 0]) : 0.f;
      ppf1 = (prok && ptc0 + 1 < nkn) ? bf2f(prow[ptc0 + 1]) : 0.f;
      ppf2 = (prok && ptc0 + 2 < nkn) ? bf2f(prow[ptc0 + 2]) : 0.f;
    }
    // S = Q K^T
    f32x4 S[4];
#pragma unroll
    for (int nt = 0; nt < 4; nt++) S[nt] = (f32x4){0.f, 0.f, 0.f, 0.f};
#pragma unroll
    for (int nt = 0; nt < 4; nt++) {
      bf16x8 kf0 = *(const bf16x8*)&Ks[(nt * 16 + l15) * 72 + quad * 8];
      bf16x8 kf1 = *(const bf16x8*)&Ks[(nt * 16 + l15) * 72 + 32 + quad * 8];
      S[nt] = __builtin_amdgcn_mfma_f32_16x16x32_bf16(qf0, kf0, S[nt], 0, 0, 0);
      S[nt] = __builtin_amdgcn_mfma_f32_16x16x32_bf16(qf1, kf1, S[nt], 0, 0, 0);
    }
    int okp[4]; bool cval[4];
#pragma unroll
    for (int nt = 0; nt < 4; nt++) {
      int c = kbCur + nt * 16 + l15;
      cval[nt] = c < T_TOK;
      okp[nt] = (c < 8 ? c : 8 + ((c - 8) >> 2)) - ok0c;
    }
#pragma unroll
    for (int r = 0; r < 4; r++) {
      int pr = wave * 16 + quad * 4 + r;
#pragma unroll
      for (int nt = 0; nt < 4; nt++) {
        float a = cval[nt] ? fminf(S[nt][r] + pt[myq[r] * 24 + okp[nt]], 86.f) : -1e30f;
        Ps[pr * 72 + nt * 16 + l15] = f2bf(EXP2(a));
      }
    }
    // O += P V  — Ps rows are wave-local (written & read by same wave): no barrier
    bf16x8 pa0 = *(const bf16x8*)&Ps[(wave * 16 + l15) * 72 + quad * 8];
    bf16x8 pa1 = *(const bf16x8*)&Ps[(wave * 16 + l15) * 72 + 32 + quad * 8];
#pragma unroll
    for (int nt = 0; nt < 5; nt++) {
      bf16x8 vb0 = *(const bf16x8*)&Vs[(nt * 16 + l15) * 88 + quad * 8];
      bf16x8 vb1 = *(const bf16x8*)&Vs[(nt * 16 + l15) * 88 + 32 + quad * 8];
      O[nt] = __builtin_amdgcn_mfma_f32_16x16x32_bf16(pa0, vb0, O[nt], 0, 0, 0);
      O[nt] = __builtin_amdgcn_mfma_f32_16x16x32_bf16(pa1, vb1, O[nt], 0, 0, 0);
    }
  }
#pragma unroll
  for (int r = 0; r < 4; r++) {
    int orow = q0 + wave * 16 + quad * 4 + r;
    size_t base = ((size_t)(z * NHEAD + h) * TK + orow);
    if (l15 == 0) lbuf[base] = O[4][r];
#pragma unroll
    for (int nt = 0; nt < 4; nt++)
      Opart[base * 64 + nt * 16 + l15] = f2bf(O[nt][r]);
  }
}

// ---------------- merge flash splits (pure sum; m==0) -> ob (bf16 [T][512]) ---------

__global__ __launch_bounds__(256) void flash_merge(
    const unsigned short* __restrict__ Opart, const float* __restrict__ lbuf,
    unsigned short* __restrict__ ob)
{
  int idx = blockIdx.x * 256 + threadIdx.x;
  if (idx >= T_TOK * HIDDEN) return;
  int row = idx >> 9, c = idx & 511;
  int h = c >> 6, d = c & 63;
  float num = 0.f, den = 0.f;
#pragma unroll
  for (int s = 0; s < FSPLIT; s++) {
    size_t base = ((size_t)(s * NHEAD + h) * TK + row);
    den += lbuf[base];
    num += bf2f(Opart[base * 64 + d]);
  }
  ob[idx] = f2bf(num / den);
}

// ---------------- residual + bias + 4-way split-K sum + LN, fp32 + bf16 mirror -------

__global__ __launch_bounds__(256) void ln_residual4(
    float* __restrict__ x, const float* __restrict__ parts,
    const float* __restrict__ bias,
    const float* __restrict__ g, const float* __restrict__ b,
    unsigned short* __restrict__ xb)
{
  __shared__ float sb[4];
  int row = blockIdx.x;
  int j0 = threadIdx.x, j1 = threadIdx.x + 256;
  int base = row * HIDDEN;
  const size_t ss = (size_t)TP * HIDDEN;
  float v0 = x[base + j0] + bias[j0] + parts[base + j0] + parts[ss + base + j0]
           + parts[2 * ss + base + j0] + parts[3 * ss + base + j0];
  float v1 = x[base + j1] + bias[j1] + parts[base + j1] + parts[ss + base + j1]
           + parts[2 * ss + base + j1] + parts[3 * ss + base + j1];
  float s1 = blockReduceSum(v0 + v1, sb);
  float s2 = blockReduceSum(v0 * v0 + v1 * v1, sb);
  float m = s1 * (1.0f / HIDDEN);
  float var = s2 * (1.0f / HIDDEN) - m * m;
  float inv = rsqrtf(var + 1e-5f);
  float y0 = (v0 - m) * inv * g[j0] + b[j0];
  float y1 = (v1 - m) * inv * g[j1] + b[j1];
  x[base + j0] = y0;
  x[base + j1] = y1;
  xb[base + j0] = f2bf(y0);
  xb[base + j1] = f2bf(y1);
}

__global__ __launch_bounds__(256) void copy_out(
    const float4* __restrict__ src, float4* __restrict__ dst, int n4)
{
  int i = blockIdx.x * 256 + threadIdx.x;
  if (i < n4) dst[i] = src[i];
}

// ---------------- driver ----------------

extern "C" void kernel_launch(void* const* d_in, const int* in_sizes, int n_in,
                              void* d_out, int out_size, void* d_ws, size_t ws_size,
                              hipStream_t stream) {
  const float* obj   = (const float*)d_in[0];
  const float* st0   = (const float*)d_in[2];
  const int*   rpe_a = (const int*)d_in[3];
  const int*   rpe_d = (const int*)d_in[4];
  const float* mask  = (const float*)d_in[5];
  const float* Wpg = (const float*)d_in[6];  const float* bpg = (const float*)d_in[7];
  const float* pg_g = (const float*)d_in[8]; const float* pg_b = (const float*)d_in[9];
  const float* Wps = (const float*)d_in[10]; const float* bps = (const float*)d_in[11];
  const float* ps_g = (const float*)d_in[12];const float* ps_b = (const float*)d_in[13];
  const float* emb_a = (const float*)d_in[14];
  const float* emb_d = (const float*)d_in[15];
  const float* Wq = (const float*)d_in[16]; const float* bq = (const float*)d_in[17];
  const float* Wk = (const float*)d_in[18]; const float* bk = (const float*)d_in[19];
  const float* Wv = (const float*)d_in[20]; const float* bv = (const float*)d_in[21];
  const float* Wo = (const float*)d_in[22]; const float* bo = (const float*)d_in[23];
  const float* W1 = (const float*)d_in[24]; const float* b1 = (const float*)d_in[25];
  const float* W2 = (const float*)d_in[26]; const float* b2 = (const float*)d_in[27];
  const float* ln1_g = (const float*)d_in[28]; const float* ln1_b = (const float*)d_in[29];
  const float* ln2_g = (const float*)d_in[30]; const float* ln2_b = (const float*)d_in[31];

  // ---- workspace layout ----
  char* p = (char*)d_ws;
  auto alloc = [&](size_t bytes) { char* q = p; p += (bytes + 255) & ~(size_t)255; return q; };
  float*          x      = (float*)alloc((size_t)T_TOK * HIDDEN * 4);
  unsigned short* xb     = (unsigned short*)alloc((size_t)TP * HIDDEN * 2);
  // union1: {qhb,khb,vhb,vtb} (attention phase) | hb (FFN phase)
  char*           u1     = (char*)alloc((size_t)TP * FFDIM * 2);
  unsigned short* qhb    = (unsigned short*)u1;
  unsigned short* khb    = qhb + (size_t)NHEAD * TP * ADIM;
  unsigned short* vhb    = khb + (size_t)NHEAD * TP * ADIM;
  unsigned short* vtb    = vhb + (size_t)NHEAD * TP * ADIM;
  unsigned short* hb     = (unsigned short*)u1;
  unsigned short* ob     = (unsigned short*)alloc((size_t)TP * HIDDEN * 2);
  // union2: {Opart(bf16)+lbuf} (flash) | parts (split-K GEMM fp32)
  size_t opartB = (size_t)FSPLIT * NHEAD * TK * ADIM * 2;
  size_t partsB = (size_t)NSPLIT * TP * HIDDEN * 4;
  size_t u2B = opartB + (size_t)FSPLIT * NHEAD * TK * 4;
  if (partsB > u2B) u2B = partsB;
  char*           u2     = (char*)alloc(u2B);
  unsigned short* Opart  = (unsigned short*)u2;
  float*          lbb    = (float*)(u2 + opartB);
  float*          parts  = (float*)u2;
  unsigned short* posb   = (unsigned short*)alloc((size_t)NHEAD * NORIG * NORIG * 2);
  size_t perLayerW = ((size_t)1536 * 512 + 512 * 512 + 2048 * 512 + 512 * 2048) * 2;
  size_t baseUsed = (size_t)(p - (char*)d_ws);
  bool hoist = (baseUsed + 6 * perLayerW + 2048) <= ws_size;
  int nWsets = hoist ? 6 : 1;
  unsigned short* Wsets = (unsigned short*)alloc(perLayerW * nWsets);
  if ((size_t)(p - (char*)d_ws) > ws_size) return;

  auto wq_t = [&](int l) { return Wsets + (hoist ? l : 0) * (perLayerW / 2); };
  auto wo_t = [&](int l) { return wq_t(l) + (size_t)1536 * 512; };
  auto w1_t = [&](int l) { return wo_t(l) + (size_t)512 * 512; };
  auto w2_t = [&](int l) { return w1_t(l) + (size_t)2048 * 512; };

  float* out = (float*)d_out;

  embed_kernel<<<T_TOK, 256, 0, stream>>>(obj, st0, Wpg, bpg, pg_g, pg_b,
                                          Wps, bps, ps_g, ps_b, x, xb);
  padzero<<<((TP - T_TOK) * HIDDEN + 255) / 256, 256, 0, stream>>>(xb);
  posbuild<<<NORIG, 256, 0, stream>>>(rpe_a, rpe_d, emb_a, emb_d, mask, posb);
  if (hoist) {
    for (int l = 0; l < NLAYER; l++)
      wtrans<<<768, 256, 0, stream>>>(
          Wq + l * 512 * 512, Wk + l * 512 * 512, Wv + l * 512 * 512,
          Wo + l * 512 * 512, W1 + l * 512 * 2048, W2 + l * 2048 * 512,
          wq_t(l), wo_t(l), w1_t(l), w2_t(l));
  }

  for (int l = 0; l < NLAYER; l++) {
    if (!hoist) {
      wtrans<<<768, 256, 0, stream>>>(
          Wq + l * 512 * 512, Wk + l * 512 * 512, Wv + l * 512 * 512,
          Wo + l * 512 * 512, W1 + l * 512 * 2048, W2 + l * 2048 * 512,
          wq_t(l), wo_t(l), w1_t(l), w2_t(l));
    }
    // QKV (N=1536 packed)
    gemm_bt<<<dim3(12, 34, 1), 256, 0, stream>>>(
        xb, HIDDEN, wq_t(l), HIDDEN, HIDDEN, 0,
        bq + l * 512, bk + l * 512, bv + l * 512, qhb, khb, vhb, nullptr, 0);
    vt_trans<<<dim3(33, 8), 256, 0, stream>>>(vhb, vtb);
    flash_attn<<<dim3(33, 8, FSPLIT), 256, 0, stream>>>(
        qhb, khb, vtb, posb, Opart, lbb);
    flash_merge<<<(T_TOK * HIDDEN + 255) / 256, 256, 0, stream>>>(Opart, lbb, ob);
    // O projection: split-K(4) -> parts, reduce fused into LN
    gemm_bt<<<dim3(4, 34, NSPLIT), 256, 0, stream>>>(
        ob, HIDDEN, wo_t(l), HIDDEN, HIDDEN, 1,
        nullptr, nullptr, nullptr, nullptr, nullptr, nullptr, parts, HIDDEN);
    ln_residual4<<<T_TOK, 256, 0, stream>>>(x, parts, bo + l * 512,
                                            ln1_g + l * 512, ln1_b + l * 512, xb);
    // FFN1 -> hb (bf16, leaky)
    gemm_bt<<<dim3(16, 34, 1), 256, 0, stream>>>(
        xb, HIDDEN, w1_t(l), HIDDEN, HIDDEN, 2,
        b1 + l * 2048, nullptr, nullptr, hb, nullptr, nullptr, nullptr, FFDIM);
    // FFN2: split-K(4) -> parts
    gemm_bt<<<dim3(4, 34, NSPLIT), 256, 0, stream>>>(
        hb, FFDIM, w2_t(l), FFDIM, FFDIM, 1,
        nullptr, nullptr, nullptr, nullptr, nullptr, nullptr, parts, HIDDEN);
    ln_residual4<<<T_TOK, 256, 0, stream>>>(x, parts, b2 + l * 512,
                                            ln2_g + l * 512, ln2_b + l * 512, xb);
  }

  int n4 = T_TOK * HIDDEN / 4;
  copy_out<<<(n4 + 255) / 256, 256, 0, stream>>>((const float4*)x, (float4*)out, n4);
}